// Round 8
// baseline (2132.980 us; speedup 1.0000x reference)
//
#include <hip/hip_runtime.h>
#include <cstdint>
#include <cstddef>

using bf16 = __bf16;
typedef __bf16 bf16x8 __attribute__((ext_vector_type(8)));
typedef __bf16 bf16x4 __attribute__((ext_vector_type(4)));
typedef __bf16 bf16x2 __attribute__((ext_vector_type(2)));
typedef float  f32x4  __attribute__((ext_vector_type(4)));
typedef float  f32x16 __attribute__((ext_vector_type(16)));
typedef int    i32x4  __attribute__((ext_vector_type(4)));
typedef float  f32x4u __attribute__((ext_vector_type(4), aligned(4)));  // 4B-aligned vec load

// ---- problem constants ----
constexpr int NB   = 2;      // batch
constexpr int NN   = 2048;   // seq
constexpr int DIM  = 1024;
constexpr int NH   = 8;
constexpr int DH   = 64;
constexpr int INNER= 512;
constexpr int QKVN = 640;    // fused Q(512) + K(64) + V(64) projection width
constexpr int FF   = 2730;
constexpr int FFP  = 2816;   // padded FF (22*128)
constexpr int FF2N = 5632;   // fused a|g FF1 output width
constexpr int MROW = NB * NN;   // 4096
constexpr int NLAY = 6;
constexpr int AROWS = NB * NH * NN;  // 32768 attention (b,h,q) rows

// async global->LDS, 16B per lane; LDS dest is wave-uniform base (+lane*16 by HW)
__device__ __forceinline__ void gload_lds16(const bf16* g, bf16* l) {
  __builtin_amdgcn_global_load_lds((const __attribute__((address_space(1))) void*)g,
                                   (__attribute__((address_space(3))) void*)l,
                                   16, 0, 0);
}

__device__ __forceinline__ int pack_bf16(float lo, float hi_) {
  bf16x2 t; t[0] = (bf16)lo; t[1] = (bf16)hi_;
  return __builtin_bit_cast(int, t);
}

// ======================= bias table ==========================
__global__ void btab_kernel(const float* __restrict__ rel, float* __restrict__ btab) {
  int d = blockIdx.x * 256 + threadIdx.x;
  if (d >= NN) return;
  int bucket;
  if (d < 16) bucket = d;
  else {
    int vl = 16 + (int)(logf((float)d / 16.0f) / logf(8.0f) * 16.0f);
    bucket = vl < 31 ? vl : 31;
  }
  for (int h = 0; h < NH; ++h) btab[h * NN + d] = rel[bucket * NH + h];
}

// ============== weight convert + transpose (+pad, +scale) ==============
__global__ void conv_tr(const float* __restrict__ src, size_t srcLayer, int srcStride,
                        int colOff, int R, int C,
                        bf16* __restrict__ dst, size_t dstLayer, int Tcols, float scale) {
  __shared__ float tile[32][33];
  const int i0 = blockIdx.x * 32, j0 = blockIdx.y * 32, z = blockIdx.z;
  const float* s = src + (size_t)z * srcLayer;
  bf16* d = dst + (size_t)z * dstLayer;
  const int tx = threadIdx.x, ty = threadIdx.y;
#pragma unroll
  for (int k = 0; k < 4; ++k) {
    int j = j0 + ty + k * 8;
    int i = i0 + tx;
    float v = 0.0f;
    if (j < R && i < C) v = s[(size_t)j * srcStride + colOff + i] * scale;
    tile[ty + k * 8][tx] = v;
  }
  __syncthreads();
#pragma unroll
  for (int k = 0; k < 4; ++k) {
    int i = i0 + ty + k * 8;   // dst row
    int j = j0 + tx;           // dst col
    d[(size_t)i * Tcols + j] = (bf16)tile[tx][ty + k * 8];
  }
}

// ======================= LayerNorm ==========================
template <typename OUT>
__global__ void ln_kernel(const float* __restrict__ X, const float* __restrict__ G,
                          const float* __restrict__ Bt, OUT* __restrict__ out) {
  __shared__ float red[8];
  const int row = blockIdx.x, t = threadIdx.x;
  const float* xr = X + (size_t)row * DIM;
  float4 v = *(const float4*)(xr + t * 4);
  float s  = v.x + v.y + v.z + v.w;
  float s2 = v.x * v.x + v.y * v.y + v.z * v.z + v.w * v.w;
#pragma unroll
  for (int o = 1; o < 64; o <<= 1) { s += __shfl_xor(s, o); s2 += __shfl_xor(s2, o); }
  if ((t & 63) == 0) { red[t >> 6] = s; red[4 + (t >> 6)] = s2; }
  __syncthreads();
  float S  = red[0] + red[1] + red[2] + red[3];
  float S2 = red[4] + red[5] + red[6] + red[7];
  const float inv = 1.0f / (float)DIM;
  float mu = S * inv;
  float var = S2 * inv - mu * mu;
  float rstd = rsqrtf(var + 1e-5f);
  float4 g  = *(const float4*)(G + t * 4);
  float4 bb = *(const float4*)(Bt + t * 4);
  OUT* orow = out + (size_t)row * DIM + t * 4;
  orow[0] = (OUT)((v.x - mu) * rstd * g.x + bb.x);
  orow[1] = (OUT)((v.y - mu) * rstd * g.y + bb.y);
  orow[2] = (OUT)((v.z - mu) * rstd * g.z + bb.z);
  orow[3] = (OUT)((v.w - mu) * rstd * g.w + bb.w);
}

// ======================= GEMM: C[M,N] = A[M,K] @ B^T[N,K] ==========================
// 128x128 tile, BK=64, 8 waves (2Mx4N, 64x32 each). TRIPLE-buffered LDS with
// prefetch distance 2 + counted vmcnt (T4): DMA issued at step t is consumed at
// t+2, so ~900cy HBM latency hides under 2 MFMA phases. Per-wave vmcnt ledger:
// top of step t has 8 outstanding (STAGE t: 4, STAGE t+1: 4); vmcnt(4) retires
// exactly STAGE(t); barrier; STAGE(t+2) overwrites buffer (t-1)%3 whose readers
// passed the barrier. ONE barrier per K-step; vmcnt(0) only at the tail.
// Swizzle per m173/rule#21: pre-swizzled GLOBAL source col + linear LDS dest +
// XOR on read (bank-conflict 0, verified r6). XCD block swizzle (nwg%8==0).
template <int MODE>  // 0: store bf16 C;  1: Xr += acc (fp32 residual)
__launch_bounds__(512)
__global__ void gemm_bt(const bf16* __restrict__ A, const bf16* __restrict__ B,
                        int K, int lda, int N, bf16* __restrict__ Cb, float* __restrict__ Xr) {
  __shared__ __align__(16) bf16 As[3][128 * 64];
  __shared__ __align__(16) bf16 Bs[3][128 * 64];
  const int tid = threadIdx.x;
  const int lane = tid & 63, wave = tid >> 6;
  const int gx = gridDim.x, gy = gridDim.y;
  const int nwg = gx * gy;
  const int orig = blockIdx.y * gx + blockIdx.x;
  const int wgid = (orig & 7) * (nwg >> 3) + (orig >> 3);  // XCD swizzle (nwg%8==0)
  const int m0 = (wgid % gy) * 128;   // M fastest within XCD chunk -> B-panel L2 reuse
  const int n0 = (wgid / gy) * 128;
  const int wm = (wave >> 2) * 64, wn = (wave & 3) * 32;
  const int fr = lane & 15, fg8 = (lane >> 4) * 8;
  const int frl8 = (fr & 7) * 8;           // read-side swizzle XOR
  const int rL = lane >> 3;                // staging row within 8-row group
  const int cS = ((lane & 7) ^ rL) * 8;    // pre-swizzled global source col
  const bf16* aB = A + (size_t)(m0 + wave * 8 + rL) * lda + cS;
  const bf16* bB = B + (size_t)(n0 + wave * 8 + rL) * K + cS;
  f32x4 acc[4][2] = {};

  auto STAGE = [&](int buf, int kt) {   // 4 vmcnt events per wave
#pragma unroll
    for (int r = 0; r < 2; ++r) {
      gload_lds16(aB + (size_t)(r * 64) * lda + kt, &As[buf][(r * 8 + wave) * 512]);
      gload_lds16(bB + (size_t)(r * 64) * K + kt, &Bs[buf][(r * 8 + wave) * 512]);
    }
  };

  const int nt = K >> 6;   // >= 8 for all our shapes
  STAGE(0, 0);
  STAGE(1, 64);
  int cur = 0, stg = 2;
  for (int t = 0; t < nt; ++t) {
    if (t + 1 < nt) asm volatile("s_waitcnt vmcnt(4)" ::: "memory");  // STAGE(t) done
    else            asm volatile("s_waitcnt vmcnt(0)" ::: "memory");
    __builtin_amdgcn_s_barrier();      // all waves: buf[cur] staged; buf[stg] readers done
    __builtin_amdgcn_sched_barrier(0);
    if (t + 2 < nt) STAGE(stg, (t + 2) * 64);   // in flight across TWO compute phases
#pragma unroll
    for (int kk = 0; kk < 64; kk += 32) {
      bf16x8 af[4], bfr[2];
#pragma unroll
      for (int m = 0; m < 4; ++m)
        af[m] = *(const bf16x8*)&As[cur][(wm + m * 16 + fr) * 64 + ((kk + fg8) ^ frl8)];
#pragma unroll
      for (int n = 0; n < 2; ++n)
        bfr[n] = *(const bf16x8*)&Bs[cur][(wn + n * 16 + fr) * 64 + ((kk + fg8) ^ frl8)];
#pragma unroll
      for (int m = 0; m < 4; ++m)
#pragma unroll
        for (int n = 0; n < 2; ++n)
          acc[m][n] = __builtin_amdgcn_mfma_f32_16x16x32_bf16(af[m], bfr[n], acc[m][n], 0, 0, 0);
    }
    __builtin_amdgcn_sched_barrier(0);
    cur = (cur == 2) ? 0 : cur + 1;
    stg = (stg == 2) ? 0 : stg + 1;
  }
  const int cc = lane & 15, cg = (lane >> 4) * 4;
#pragma unroll
  for (int m = 0; m < 4; ++m) {
#pragma unroll
    for (int n = 0; n < 2; ++n) {
      const int col = n0 + wn + n * 16 + cc;
#pragma unroll
      for (int r = 0; r < 4; ++r) {
        const int row = m0 + wm + m * 16 + cg + r;
        const size_t idx = (size_t)row * N + col;
        if (MODE == 0) Cb[idx] = (bf16)acc[m][n][r];
        else           Xr[idx] += acc[m][n][r];
      }
    }
  }
}

// ======================= V transpose: VT[b][dh][n] = QKV[b*NN+n][576+dh] ==========
__global__ void vt_kernel(const bf16* __restrict__ QKV, bf16* __restrict__ VT) {
  __shared__ bf16 t[32][33];
  const int n0 = blockIdx.x * 32, d0 = blockIdx.y * 32, b = blockIdx.z;
  const int tx = threadIdx.x, ty = threadIdx.y;
#pragma unroll
  for (int k = 0; k < 4; ++k) {
    int n = n0 + ty + k * 8;
    t[ty + k * 8][tx] = QKV[(size_t)(b * NN + n) * QKVN + 576 + d0 + tx];
  }
  __syncthreads();
#pragma unroll
  for (int k = 0; k < 4; ++k) {
    int dh = d0 + ty + k * 8;
    VT[(size_t)(b * 64 + dh) * NN + n0 + tx] = t[tx][ty + k * 8];
  }
}

// ======================= attention: 32x32 MFMA, in-register softmax ==============
// 4 waves/block = 4 heads (MQA: K/V shared -> L1 reuse), no barriers, no LDS.
__launch_bounds__(256)
__global__ void attn_kernel(const bf16* __restrict__ QKV, const bf16* __restrict__ VT,
                            const float* __restrict__ btab,
                            float* __restrict__ Opart, float* __restrict__ mlbuf) {
  const int tid = threadIdx.x;
  const int lane = tid & 63, wv = tid >> 6;
  const int split = blockIdx.x & 1;
  const int qt = (NN / 32 - 1) - (blockIdx.x >> 1);   // longest-first
  const int h = blockIdx.y * 4 + wv, b = blockIdx.z;
  const int q0 = qt * 32;
  const int qc = lane & 31;        // q col (also A-operand row index, also V^T d row)
  const int hid = lane >> 5;
  const int h8 = hid * 8;
  const int kv_full = q0 + 32;
  const int half = (kv_full > 32) ? ((kv_full / 2) & ~31) : 0;
  const int lo = split ? half : 0;
  const int kend = split ? kv_full : half;
  const size_t obase = ((size_t)split * NB * NH + b * NH + h) * 64;  // Opart row base
  const int Rbase = (b * NH + h) * NN + q0;
  if (kend <= lo) {   // empty split: zero partial block, weight 0 in combine
#pragma unroll
    for (int dd = 0; dd < 32; ++dd)
      Opart[(obase + dd * 2 + hid) * NN + q0 + qc] = 0.0f;
    if (hid == 0)
      ((float2*)mlbuf)[(size_t)split * AROWS + Rbase + qc] = make_float2(-1e30f, 0.0f);
    return;
  }
  const float* bt = btab + h * NN;
  bf16x8 qf[4];
#pragma unroll
  for (int ks = 0; ks < 4; ++ks)
    qf[ks] = *(const bf16x8*)&QKV[(size_t)(b * NN + q0 + qc) * QKVN + h * DH + ks * 16 + h8];

  f32x16 Oacc0 = {}, Oacc1 = {};
  float m_run = -1e30f, l_run = 0.0f;
  int kv0 = lo;

  while (kv0 < kend) {
    const bool interior = (kv0 + 32 <= q0);
    bf16x8 kf[4];
#pragma unroll
    for (int ks = 0; ks < 4; ++ks)
      kf[ks] = *(const bf16x8*)&QKV[(size_t)(b * NN + kv0 + qc) * QKVN + 512 + ks * 16 + h8];
    bf16x8 vf[2][2];
#pragma unroll
    for (int dblk = 0; dblk < 2; ++dblk)
#pragma unroll
      for (int ks2 = 0; ks2 < 2; ++ks2)
        vf[dblk][ks2] = *(const bf16x8*)&VT[(size_t)(b * 64 + dblk * 32 + qc) * NN + kv0 + ks2 * 16 + h8];
    __builtin_amdgcn_s_setprio(1);
    f32x16 S = {};
#pragma unroll
    for (int ks = 0; ks < 4; ++ks)
      S = __builtin_amdgcn_mfma_f32_32x32x16_bf16(kf[ks], qf[ks], S, 0, 0, 0);
    __builtin_amdgcn_s_setprio(0);
    float sv[16];
    float mx = -1e30f;
    if (interior) {
      f32x4 bv[4];
#pragma unroll
      for (int g = 0; g < 4; ++g)
        bv[g] = *(const f32x4u*)(bt + (q0 + qc - kv0 - 8 * g - 4 * hid - 3));
#pragma unroll
      for (int g = 0; g < 4; ++g)
#pragma unroll
        for (int e = 0; e < 4; ++e) {
          const float val = S[g * 4 + e] + bv[g][3 - e];
          sv[g * 4 + e] = val;
          mx = fmaxf(mx, val);
        }
    } else {
#pragma unroll
      for (int r = 0; r < 16; ++r) {
        const int kvr = (r & 3) + 8 * (r >> 2) + 4 * hid;
        const int d = (q0 + qc) - (kv0 + kvr);
        const int dc = d > 0 ? d : 0;
        float val = S[r] + bt[dc];
        if (d < 0) val = -1e30f;
        sv[r] = val;
        mx = fmaxf(mx, val);
      }
    }
    if (!__all(mx <= m_run + 8.0f)) {
      mx = fmaxf(mx, __shfl_xor(mx, 32));
      const float m_new = fmaxf(m_run, mx);
      const float sc = __expf(m_run - m_new);
      l_run *= sc;
#pragma unroll
      for (int r = 0; r < 16; ++r) { Oacc0[r] *= sc; Oacc1[r] *= sc; }
      m_run = m_new;
    }
    float csum = 0.0f;
#pragma unroll
    for (int r = 0; r < 16; ++r) { sv[r] = __expf(sv[r] - m_run); csum += sv[r]; }
    csum += __shfl_xor(csum, 32);
    l_run += csum;
    int w[8];
#pragma unroll
    for (int g = 0; g < 4; ++g) {
      w[2 * g]     = pack_bf16(sv[4 * g],     sv[4 * g + 1]);
      w[2 * g + 1] = pack_bf16(sv[4 * g + 2], sv[4 * g + 3]);
    }
    bf16x8 pfrag[2];
#pragma unroll
    for (int ks2 = 0; ks2 < 2; ++ks2) {
      const int a  = w[4 * ks2],     bb = w[4 * ks2 + 1];
      const int c  = w[4 * ks2 + 2], dd = w[4 * ks2 + 3];
      const int s0 = hid ? a : c,    s1 = hid ? bb : dd;
      const int r0 = __shfl_xor(s0, 32);
      const int r1 = __shfl_xor(s1, 32);
      i32x4 fw;
      fw[0] = hid ? r0 : a;
      fw[1] = hid ? r1 : bb;
      fw[2] = hid ? c  : r0;
      fw[3] = hid ? dd : r1;
      pfrag[ks2] = __builtin_bit_cast(bf16x8, fw);
    }
    __builtin_amdgcn_s_setprio(1);
#pragma unroll
    for (int ks2 = 0; ks2 < 2; ++ks2) {
      Oacc0 = __builtin_amdgcn_mfma_f32_32x32x16_bf16(vf[0][ks2], pfrag[ks2], Oacc0, 0, 0, 0);
      Oacc1 = __builtin_amdgcn_mfma_f32_32x32x16_bf16(vf[1][ks2], pfrag[ks2], Oacc1, 0, 0, 0);
    }
    __builtin_amdgcn_s_setprio(0);
    kv0 += 32;
  }
#pragma unroll
  for (int r = 0; r < 16; ++r) {
    const int dl = (r & 3) + 8 * (r >> 2) + 4 * hid;
    Opart[(obase + dl) * NN + q0 + qc]      = Oacc0[r];
    Opart[(obase + 32 + dl) * NN + q0 + qc] = Oacc1[r];
  }
  if (hid == 0)
    ((float2*)mlbuf)[(size_t)split * AROWS + Rbase + qc] = make_float2(m_run, l_run);
}

// ======================= combine split-KV partials -> O (bf16) =================
__global__ void attn_combine(const float* __restrict__ Opart, const float* __restrict__ mlbuf,
                             bf16* __restrict__ O) {
  const int gtid = blockIdx.x * 256 + threadIdx.x;   // NB*NH*16*NN threads
  const int q  = gtid & (NN - 1);
  const int dq = (gtid >> 11) & 15;
  const int bh = gtid >> 15;                          // b*NH + h
  const int R = bh * NN + q;
  const float2 ml0 = ((const float2*)mlbuf)[R];
  const float2 ml1 = ((const float2*)mlbuf)[AROWS + R];
  const float m = fmaxf(ml0.x, ml1.x);
  const float w0 = __expf(ml0.x - m), w1 = __expf(ml1.x - m);
  const float inv = 1.0f / (ml0.y * w0 + ml1.y * w1);
  const size_t r0 = ((size_t)bh * 64 + dq * 4) * NN + q;
  const size_t r1 = ((size_t)(NB * NH + bh) * 64 + dq * 4) * NN + q;
  bf16x4 res;
#pragma unroll
  for (int j = 0; j < 4; ++j)
    res[j] = (bf16)((Opart[r0 + j * NN] * w0 + Opart[r1 + j * NN] * w1) * inv);
  const int h = bh & (NH - 1), b = bh >> 3;
  *(bf16x4*)&O[(size_t)(b * NN + q) * INNER + h * DH + dq * 4] = res;
}

// ======================= GEGLU elementwise on fused h buffer ====================
// h[row][0..2815]=a, h[row][2816..5631]=g; writes gelu(g)*a into h[row][0..2815].
__global__ void gelu_mul_kernel(bf16* __restrict__ h) {
  const size_t total = (size_t)MROW * FFP / 8;
  for (size_t i = (size_t)blockIdx.x * blockDim.x + threadIdx.x; i < total;
       i += (size_t)gridDim.x * blockDim.x) {
    const size_t row = i / (FFP / 8), c8 = i % (FFP / 8);
    bf16* base = h + row * FF2N + c8 * 8;
    bf16x8 a = *(const bf16x8*)base;
    bf16x8 g = *(const bf16x8*)(base + FFP);
    bf16x8 r;
#pragma unroll
    for (int j = 0; j < 8; ++j) {
      float gv = (float)g[j], av = (float)a[j];
      float ge = 0.5f * gv * (1.0f + erff(gv * 0.70710678118654752f));
      r[j] = (bf16)(ge * av);
    }
    *(bf16x8*)base = r;
  }
}

// ======================= launch ==========================
extern "C" void kernel_launch(void* const* d_in, const int* in_sizes, int n_in,
                              void* d_out, int out_size, void* d_ws, size_t ws_size,
                              hipStream_t stream) {
  (void)in_sizes; (void)n_in; (void)out_size;
  const float* in_x  = (const float*)d_in[0];
  const float* rel   = (const float*)d_in[1];
  const float* ln1g  = (const float*)d_in[2];
  const float* ln1b  = (const float*)d_in[3];
  const float* wq    = (const float*)d_in[4];
  const float* wkv   = (const float*)d_in[5];
  const float* wo    = (const float*)d_in[6];
  const float* ln2g  = (const float*)d_in[7];
  const float* ln2b  = (const float*)d_in[8];
  const float* w1    = (const float*)d_in[9];
  const float* w2    = (const float*)d_in[10];
  const float* lnfg  = (const float*)d_in[11];
  const float* lnfb  = (const float*)d_in[12];
  float* out = (float*)d_out;

  constexpr size_t E_QKV = (size_t)QKVN * DIM;   // fused wq|wkv, [640][1024]
  constexpr size_t E_WO  = (size_t)DIM * INNER;
  constexpr size_t E_W1F = (size_t)FF2N * DIM;   // fused [5632][1024] (a rows then g rows)
  constexpr size_t E_W2  = (size_t)DIM * FFP;
  bf16* wqkvT = (bf16*)d_ws;
  bf16* woT  = wqkvT + NLAY * E_QKV;
  bf16* w1fT = woT  + NLAY * E_WO;
  bf16* w2T  = w1fT + NLAY * E_W1F;
  bf16* xnb  = w2T  + NLAY * E_W2;
  bf16* qkvb = xnb  + (size_t)MROW * DIM;
  bf16* vTb  = qkvb + (size_t)MROW * QKVN;
  bf16* ob   = vTb  + (size_t)NB * 64 * NN;
  bf16* hb   = ob   + (size_t)MROW * INNER;      // fused [4096][5632]
  float* xbuf = (float*)(hb + (size_t)MROW * FF2N);
  float* btab = xbuf + (size_t)MROW * DIM;
  const size_t needed = (size_t)((char*)(btab + NH * NN) - (char*)d_ws);
  if (ws_size < needed) return;  // visible clean failure instead of corruption
  // attn partials overlaid on hb (idle during attention):
  float* Opart = (float*)hb;
  float* mlbuf = (float*)(hb + (size_t)19 * 1024 * 1024);   // at +38MB, 512KB
  hipMemcpyAsync(xbuf, in_x, (size_t)MROW * DIM * sizeof(float),
                 hipMemcpyDeviceToDevice, stream);
  btab_kernel<<<8, 256, 0, stream>>>(rel, btab);

  const dim3 tb(32, 8);
  conv_tr<<<dim3(16, 32, 6), tb, 0, stream>>>(wq,  (size_t)DIM*INNER, INNER, 0, DIM, INNER,
                                              wqkvT, E_QKV, DIM, 0.125f);  // fold DH^-0.5
  conv_tr<<<dim3(4, 32, 6),  tb, 0, stream>>>(wkv, (size_t)DIM*128, 128, 0, DIM, 128,
                                              wqkvT + (size_t)INNER*DIM, E_QKV, DIM, 1.0f);
  conv_tr<<<dim3(32, 16, 6), tb, 0, stream>>>(wo,  (size_t)INNER*DIM, DIM, 0, INNER, DIM,
                                              woT,  E_WO, INNER, 1.0f);
  conv_tr<<<dim3(88, 32, 6), tb, 0, stream>>>(w1,  (size_t)DIM*2*FF, 2*FF, 0, DIM, FF,
                                              w1fT, E_W1F, DIM, 1.0f);
  conv_tr<<<dim3(88, 32, 6), tb, 0, stream>>>(w1,  (size_t)DIM*2*FF, 2*FF, FF, DIM, FF,
                                              w1fT + (size_t)FFP*DIM, E_W1F, DIM, 1.0f);
  conv_tr<<<dim3(32, 88, 6), tb, 0, stream>>>(w2,  (size_t)FF*DIM, DIM, 0, FF, DIM,
                                              w2T,  E_W2, FFP, 1.0f);

  for (int l = 0; l < NLAY; ++l) {
    ln_kernel<bf16><<<MROW, 256, 0, stream>>>(xbuf, ln1g + l*DIM, ln1b + l*DIM, xnb);
    gemm_bt<0><<<dim3(QKVN/128, MROW/128), 512, 0, stream>>>(xnb, wqkvT + l*E_QKV, DIM, DIM, QKVN, qkvb, nullptr);
    vt_kernel<<<dim3(NN/32, 2, NB), tb, 0, stream>>>(qkvb, vTb);
    attn_kernel<<<dim3((NN/32)*2, NH/4, NB), 256, 0, stream>>>(qkvb, vTb, btab, Opart, mlbuf);
    attn_combine<<<AROWS*16/256, 256, 0, stream>>>(Opart, mlbuf, ob);
    gemm_bt<1><<<dim3(DIM/128, MROW/128), 512, 0, stream>>>(ob, woT + l*E_WO, INNER, INNER, DIM, nullptr, xbuf);
    ln_kernel<bf16><<<MROW, 256, 0, stream>>>(xbuf, ln2g + l*DIM, ln2b + l*DIM, xnb);
    gemm_bt<0><<<dim3(FF2N/128, MROW/128), 512, 0, stream>>>(xnb, w1fT + l*E_W1F, DIM, DIM, FF2N, hb, nullptr);
    gelu_mul_kernel<<<2048, 256, 0, stream>>>(hb);
    gemm_bt<1><<<dim3(DIM/128, MROW/128), 512, 0, stream>>>(hb, w2T + l*E_W2, FFP, FF2N, DIM, nullptr, xbuf);
  }
  ln_kernel<float><<<MROW, 256, 0, stream>>>(xbuf, lnfg, lnfb, out);
}

// Round 9
// 1739.661 us; speedup vs baseline: 1.2261x; 1.2261x over previous
//
#include <hip/hip_runtime.h>
#include <cstdint>
#include <cstddef>

using bf16 = __bf16;
typedef __bf16 bf16x8 __attribute__((ext_vector_type(8)));
typedef __bf16 bf16x4 __attribute__((ext_vector_type(4)));
typedef __bf16 bf16x2 __attribute__((ext_vector_type(2)));
typedef float  f32x4  __attribute__((ext_vector_type(4)));
typedef float  f32x16 __attribute__((ext_vector_type(16)));
typedef int    i32x4  __attribute__((ext_vector_type(4)));
typedef float  f32x4u __attribute__((ext_vector_type(4), aligned(4)));  // 4B-aligned vec load

// ---- problem constants ----
constexpr int NB   = 2;      // batch
constexpr int NN   = 2048;   // seq
constexpr int DIM  = 1024;
constexpr int NH   = 8;
constexpr int DH   = 64;
constexpr int INNER= 512;
constexpr int QKVN = 640;    // fused Q(512) + K(64) + V(64) projection width
constexpr int FF   = 2730;
constexpr int FFP  = 2816;   // padded FF (22*128)
constexpr int FF2N = 5632;   // fused a|g FF1 output width
constexpr int MROW = NB * NN;   // 4096
constexpr int NLAY = 6;
constexpr int AROWS = NB * NH * NN;  // 32768 attention (b,h,q) rows
constexpr int NSPLIT = 4;            // KV splits

// async global->LDS, 16B per lane; LDS dest is wave-uniform base (+lane*16 by HW)
__device__ __forceinline__ void gload_lds16(const bf16* g, bf16* l) {
  __builtin_amdgcn_global_load_lds((const __attribute__((address_space(1))) void*)g,
                                   (__attribute__((address_space(3))) void*)l,
                                   16, 0, 0);
}

__device__ __forceinline__ int pack_bf16(float lo, float hi_) {
  bf16x2 t; t[0] = (bf16)lo; t[1] = (bf16)hi_;
  return __builtin_bit_cast(int, t);
}

// ======================= bias table ==========================
__global__ void btab_kernel(const float* __restrict__ rel, float* __restrict__ btab) {
  int d = blockIdx.x * 256 + threadIdx.x;
  if (d >= NN) return;
  int bucket;
  if (d < 16) bucket = d;
  else {
    int vl = 16 + (int)(logf((float)d / 16.0f) / logf(8.0f) * 16.0f);
    bucket = vl < 31 ? vl : 31;
  }
  for (int h = 0; h < NH; ++h) btab[h * NN + d] = rel[bucket * NH + h];
}

// ============== weight convert + transpose (+pad, +scale) ==============
__global__ void conv_tr(const float* __restrict__ src, size_t srcLayer, int srcStride,
                        int colOff, int R, int C,
                        bf16* __restrict__ dst, size_t dstLayer, int Tcols, float scale) {
  __shared__ float tile[32][33];
  const int i0 = blockIdx.x * 32, j0 = blockIdx.y * 32, z = blockIdx.z;
  const float* s = src + (size_t)z * srcLayer;
  bf16* d = dst + (size_t)z * dstLayer;
  const int tx = threadIdx.x, ty = threadIdx.y;
#pragma unroll
  for (int k = 0; k < 4; ++k) {
    int j = j0 + ty + k * 8;
    int i = i0 + tx;
    float v = 0.0f;
    if (j < R && i < C) v = s[(size_t)j * srcStride + colOff + i] * scale;
    tile[ty + k * 8][tx] = v;
  }
  __syncthreads();
#pragma unroll
  for (int k = 0; k < 4; ++k) {
    int i = i0 + ty + k * 8;   // dst row
    int j = j0 + tx;           // dst col
    d[(size_t)i * Tcols + j] = (bf16)tile[tx][ty + k * 8];
  }
}

// ======================= LayerNorm ==========================
template <typename OUT>
__global__ void ln_kernel(const float* __restrict__ X, const float* __restrict__ G,
                          const float* __restrict__ Bt, OUT* __restrict__ out) {
  __shared__ float red[8];
  const int row = blockIdx.x, t = threadIdx.x;
  const float* xr = X + (size_t)row * DIM;
  float4 v = *(const float4*)(xr + t * 4);
  float s  = v.x + v.y + v.z + v.w;
  float s2 = v.x * v.x + v.y * v.y + v.z * v.z + v.w * v.w;
#pragma unroll
  for (int o = 1; o < 64; o <<= 1) { s += __shfl_xor(s, o); s2 += __shfl_xor(s2, o); }
  if ((t & 63) == 0) { red[t >> 6] = s; red[4 + (t >> 6)] = s2; }
  __syncthreads();
  float S  = red[0] + red[1] + red[2] + red[3];
  float S2 = red[4] + red[5] + red[6] + red[7];
  const float inv = 1.0f / (float)DIM;
  float mu = S * inv;
  float var = S2 * inv - mu * mu;
  float rstd = rsqrtf(var + 1e-5f);
  float4 g  = *(const float4*)(G + t * 4);
  float4 bb = *(const float4*)(Bt + t * 4);
  OUT* orow = out + (size_t)row * DIM + t * 4;
  orow[0] = (OUT)((v.x - mu) * rstd * g.x + bb.x);
  orow[1] = (OUT)((v.y - mu) * rstd * g.y + bb.y);
  orow[2] = (OUT)((v.z - mu) * rstd * g.z + bb.z);
  orow[3] = (OUT)((v.w - mu) * rstd * g.w + bb.w);
}

// ======================= GEMM: C[M,N] = A[M,K] @ B^T[N,K] ==========================
// r6-exact (best measured): 128x128 tile, BK=64, 8 waves (2Mx4N, 64x32 each),
// double-buffered LDS (64KB -> 2 blocks/CU), prefetch distance 1, 2 barriers per
// K-step. [r8 lesson: dist-2/3-buffer drops to 1 block/CU and LOSES (FETCH +75%).]
// Swizzle per m173/rule#21: pre-swizzled GLOBAL source col + linear LDS dest + XOR
// on read (bank-conflict 0, verified). XCD block swizzle (all grids %8==0).
template <int MODE>  // 0: store bf16 C;  1: Xr += acc (fp32 residual)
__launch_bounds__(512)
__global__ void gemm_bt(const bf16* __restrict__ A, const bf16* __restrict__ B,
                        int K, int lda, int N, bf16* __restrict__ Cb, float* __restrict__ Xr) {
  __shared__ __align__(16) bf16 As[2][128 * 64];
  __shared__ __align__(16) bf16 Bs[2][128 * 64];
  const int tid = threadIdx.x;
  const int lane = tid & 63, wave = tid >> 6;
  const int gx = gridDim.x, gy = gridDim.y;
  const int nwg = gx * gy;
  const int orig = blockIdx.y * gx + blockIdx.x;
  const int wgid = (orig & 7) * (nwg >> 3) + (orig >> 3);  // XCD swizzle (nwg%8==0)
  const int m0 = (wgid % gy) * 128;   // M fastest within XCD chunk -> B-panel L2 reuse
  const int n0 = (wgid / gy) * 128;
  const int wm = (wave >> 2) * 64, wn = (wave & 3) * 32;
  const int fr = lane & 15, fg8 = (lane >> 4) * 8;
  const int frl8 = (fr & 7) * 8;           // read-side swizzle XOR
  const int rL = lane >> 3;                // staging row within 8-row group
  const int cS = ((lane & 7) ^ rL) * 8;    // pre-swizzled global source col
  const bf16* aB = A + (size_t)(m0 + wave * 8 + rL) * lda + cS;
  const bf16* bB = B + (size_t)(n0 + wave * 8 + rL) * K + cS;
  f32x4 acc[4][2] = {};

  auto STAGE = [&](int buf, int kt) {
#pragma unroll
    for (int r = 0; r < 2; ++r) {
      gload_lds16(aB + (size_t)(r * 64) * lda + kt, &As[buf][(r * 8 + wave) * 512]);
      gload_lds16(bB + (size_t)(r * 64) * K + kt, &Bs[buf][(r * 8 + wave) * 512]);
    }
  };

  STAGE(0, 0);
  const int nt = K >> 6;
  int cur = 0;
  for (int t = 0; t < nt; ++t) {
    asm volatile("s_waitcnt vmcnt(0)" ::: "memory");  // buf[cur] DMA (this wave) done
    __builtin_amdgcn_s_barrier();                     // all waves' DMA done
    __builtin_amdgcn_sched_barrier(0);
    if (t + 1 < nt) STAGE(cur ^ 1, (t + 1) * 64);     // in flight across the compute
#pragma unroll
    for (int kk = 0; kk < 64; kk += 32) {
      bf16x8 af[4], bfr[2];
#pragma unroll
      for (int m = 0; m < 4; ++m)
        af[m] = *(const bf16x8*)&As[cur][(wm + m * 16 + fr) * 64 + ((kk + fg8) ^ frl8)];
#pragma unroll
      for (int n = 0; n < 2; ++n)
        bfr[n] = *(const bf16x8*)&Bs[cur][(wn + n * 16 + fr) * 64 + ((kk + fg8) ^ frl8)];
#pragma unroll
      for (int m = 0; m < 4; ++m)
#pragma unroll
        for (int n = 0; n < 2; ++n)
          acc[m][n] = __builtin_amdgcn_mfma_f32_16x16x32_bf16(af[m], bfr[n], acc[m][n], 0, 0, 0);
    }
    __builtin_amdgcn_sched_barrier(0);
    __builtin_amdgcn_s_barrier();                     // cur fully read; next STAGE may overwrite
    cur ^= 1;
  }
  const int cc = lane & 15, cg = (lane >> 4) * 4;
#pragma unroll
  for (int m = 0; m < 4; ++m) {
#pragma unroll
    for (int n = 0; n < 2; ++n) {
      const int col = n0 + wn + n * 16 + cc;
#pragma unroll
      for (int r = 0; r < 4; ++r) {
        const int row = m0 + wm + m * 16 + cg + r;
        const size_t idx = (size_t)row * N + col;
        if (MODE == 0) Cb[idx] = (bf16)acc[m][n][r];
        else           Xr[idx] += acc[m][n][r];
      }
    }
  }
}

// ======================= V transpose: VT[b][dh][n] = QKV[b*NN+n][576+dh] ==========
__global__ void vt_kernel(const bf16* __restrict__ QKV, bf16* __restrict__ VT) {
  __shared__ bf16 t[32][33];
  const int n0 = blockIdx.x * 32, d0 = blockIdx.y * 32, b = blockIdx.z;
  const int tx = threadIdx.x, ty = threadIdx.y;
#pragma unroll
  for (int k = 0; k < 4; ++k) {
    int n = n0 + ty + k * 8;
    t[ty + k * 8][tx] = QKV[(size_t)(b * NN + n) * QKVN + 576 + d0 + tx];
  }
  __syncthreads();
#pragma unroll
  for (int k = 0; k < 4; ++k) {
    int dh = d0 + ty + k * 8;
    VT[(size_t)(b * 64 + dh) * NN + n0 + tx] = t[tx][ty + k * 8];
  }
}

// ======================= attention: 32x32 MFMA, in-register softmax ==============
// 4 waves/block = 4 heads (MQA: K/V shared -> L1 reuse), no barriers, no LDS.
// NSPLIT=4 KV splits -> 1024 blocks = 4 waves/SIMD co-resident (latency hiding).
// Splits distribute 32-row KV tiles evenly; empty splits write zero partials +
// (-1e30,0) stats (combine weight exactly 0).
__launch_bounds__(256)
__global__ void attn_kernel(const bf16* __restrict__ QKV, const bf16* __restrict__ VT,
                            const float* __restrict__ btab,
                            float* __restrict__ Opart, float* __restrict__ mlbuf) {
  const int tid = threadIdx.x;
  const int lane = tid & 63, wv = tid >> 6;
  const int split = blockIdx.x & (NSPLIT - 1);
  const int qt = (NN / 32 - 1) - (blockIdx.x / NSPLIT);   // longest-first
  const int h = blockIdx.y * 4 + wv, b = blockIdx.z;
  const int q0 = qt * 32;
  const int qc = lane & 31;        // q col (also A-operand row index, also V^T d row)
  const int hid = lane >> 5;
  const int h8 = hid * 8;
  const int kv_full = q0 + 32;
  // distribute 32-row tiles among NSPLIT splits
  const int nt32 = kv_full >> 5;
  const int base = nt32 >> 2, rem = nt32 & 3;
  const int cnt = base + (split < rem ? 1 : 0);
  const int startT = split * base + (split < rem ? split : rem);
  const int lo = startT * 32;
  const int kend = lo + cnt * 32;
  const size_t obase = ((size_t)split * NB * NH + b * NH + h) * 64;  // Opart row base
  const int Rbase = (b * NH + h) * NN + q0;
  if (cnt == 0) {   // empty split: zero partial block, weight 0 in combine
#pragma unroll
    for (int dd = 0; dd < 32; ++dd)
      Opart[(obase + dd * 2 + hid) * NN + q0 + qc] = 0.0f;
    if (hid == 0)
      ((float2*)mlbuf)[(size_t)split * AROWS + Rbase + qc] = make_float2(-1e30f, 0.0f);
    return;
  }
  const float* bt = btab + h * NN;
  bf16x8 qf[4];
#pragma unroll
  for (int ks = 0; ks < 4; ++ks)
    qf[ks] = *(const bf16x8*)&QKV[(size_t)(b * NN + q0 + qc) * QKVN + h * DH + ks * 16 + h8];

  f32x16 Oacc0 = {}, Oacc1 = {};
  float m_run = -1e30f, l_run = 0.0f;
  int kv0 = lo;

  while (kv0 < kend) {
    const bool interior = (kv0 + 32 <= q0);
    bf16x8 kf[4];
#pragma unroll
    for (int ks = 0; ks < 4; ++ks)
      kf[ks] = *(const bf16x8*)&QKV[(size_t)(b * NN + kv0 + qc) * QKVN + 512 + ks * 16 + h8];
    bf16x8 vf[2][2];
#pragma unroll
    for (int dblk = 0; dblk < 2; ++dblk)
#pragma unroll
      for (int ks2 = 0; ks2 < 2; ++ks2)
        vf[dblk][ks2] = *(const bf16x8*)&VT[(size_t)(b * 64 + dblk * 32 + qc) * NN + kv0 + ks2 * 16 + h8];
    __builtin_amdgcn_s_setprio(1);
    f32x16 S = {};
#pragma unroll
    for (int ks = 0; ks < 4; ++ks)
      S = __builtin_amdgcn_mfma_f32_32x32x16_bf16(kf[ks], qf[ks], S, 0, 0, 0);
    __builtin_amdgcn_s_setprio(0);
    float sv[16];
    float mx = -1e30f;
    if (interior) {
      f32x4 bv[4];
#pragma unroll
      for (int g = 0; g < 4; ++g)
        bv[g] = *(const f32x4u*)(bt + (q0 + qc - kv0 - 8 * g - 4 * hid - 3));
#pragma unroll
      for (int g = 0; g < 4; ++g)
#pragma unroll
        for (int e = 0; e < 4; ++e) {
          const float val = S[g * 4 + e] + bv[g][3 - e];
          sv[g * 4 + e] = val;
          mx = fmaxf(mx, val);
        }
    } else {
#pragma unroll
      for (int r = 0; r < 16; ++r) {
        const int kvr = (r & 3) + 8 * (r >> 2) + 4 * hid;
        const int d = (q0 + qc) - (kv0 + kvr);
        const int dc = d > 0 ? d : 0;
        float val = S[r] + bt[dc];
        if (d < 0) val = -1e30f;
        sv[r] = val;
        mx = fmaxf(mx, val);
      }
    }
    if (!__all(mx <= m_run + 8.0f)) {
      mx = fmaxf(mx, __shfl_xor(mx, 32));
      const float m_new = fmaxf(m_run, mx);
      const float sc = __expf(m_run - m_new);
      l_run *= sc;
#pragma unroll
      for (int r = 0; r < 16; ++r) { Oacc0[r] *= sc; Oacc1[r] *= sc; }
      m_run = m_new;
    }
    float csum = 0.0f;
#pragma unroll
    for (int r = 0; r < 16; ++r) { sv[r] = __expf(sv[r] - m_run); csum += sv[r]; }
    csum += __shfl_xor(csum, 32);
    l_run += csum;
    int w[8];
#pragma unroll
    for (int g = 0; g < 4; ++g) {
      w[2 * g]     = pack_bf16(sv[4 * g],     sv[4 * g + 1]);
      w[2 * g + 1] = pack_bf16(sv[4 * g + 2], sv[4 * g + 3]);
    }
    bf16x8 pfrag[2];
#pragma unroll
    for (int ks2 = 0; ks2 < 2; ++ks2) {
      const int a  = w[4 * ks2],     bb = w[4 * ks2 + 1];
      const int c  = w[4 * ks2 + 2], dd = w[4 * ks2 + 3];
      const int s0 = hid ? a : c,    s1 = hid ? bb : dd;
      const int r0 = __shfl_xor(s0, 32);
      const int r1 = __shfl_xor(s1, 32);
      i32x4 fw;
      fw[0] = hid ? r0 : a;
      fw[1] = hid ? r1 : bb;
      fw[2] = hid ? c  : r0;
      fw[3] = hid ? dd : r1;
      pfrag[ks2] = __builtin_bit_cast(bf16x8, fw);
    }
    __builtin_amdgcn_s_setprio(1);
#pragma unroll
    for (int ks2 = 0; ks2 < 2; ++ks2) {
      Oacc0 = __builtin_amdgcn_mfma_f32_32x32x16_bf16(vf[0][ks2], pfrag[ks2], Oacc0, 0, 0, 0);
      Oacc1 = __builtin_amdgcn_mfma_f32_32x32x16_bf16(vf[1][ks2], pfrag[ks2], Oacc1, 0, 0, 0);
    }
    __builtin_amdgcn_s_setprio(0);
    kv0 += 32;
  }
#pragma unroll
  for (int r = 0; r < 16; ++r) {
    const int dl = (r & 3) + 8 * (r >> 2) + 4 * hid;
    Opart[(obase + dl) * NN + q0 + qc]      = Oacc0[r];
    Opart[(obase + 32 + dl) * NN + q0 + qc] = Oacc1[r];
  }
  if (hid == 0)
    ((float2*)mlbuf)[(size_t)split * AROWS + Rbase + qc] = make_float2(m_run, l_run);
}

// ======================= combine split-KV partials -> O (bf16) =================
// Opart layout: [split][b][h][64 d][NN q] f32. Thread: (bh, dq, q), q fastest.
__global__ void attn_combine(const float* __restrict__ Opart, const float* __restrict__ mlbuf,
                             bf16* __restrict__ O) {
  const int gtid = blockIdx.x * 256 + threadIdx.x;   // NB*NH*16*NN threads
  const int q  = gtid & (NN - 1);
  const int dq = (gtid >> 11) & 15;
  const int bh = gtid >> 15;                          // b*NH + h
  const int R = bh * NN + q;
  float2 ml[NSPLIT];
  float m = -1e30f;
#pragma unroll
  for (int s = 0; s < NSPLIT; ++s) {
    ml[s] = ((const float2*)mlbuf)[(size_t)s * AROWS + R];
    m = fmaxf(m, ml[s].x);
  }
  float w[NSPLIT];
  float denom = 0.0f;
#pragma unroll
  for (int s = 0; s < NSPLIT; ++s) {
    w[s] = __expf(ml[s].x - m);
    denom += ml[s].y * w[s];
  }
  const float inv = 1.0f / denom;
  float o[4] = {};
#pragma unroll
  for (int s = 0; s < NSPLIT; ++s) {
    const size_t rbase = ((size_t)(s * NB * NH + bh) * 64 + dq * 4) * NN + q;
#pragma unroll
    for (int j = 0; j < 4; ++j) o[j] += Opart[rbase + j * NN] * w[s];
  }
  bf16x4 res;
#pragma unroll
  for (int j = 0; j < 4; ++j) res[j] = (bf16)(o[j] * inv);
  const int h = bh & (NH - 1), b = bh >> 3;
  *(bf16x4*)&O[(size_t)(b * NN + q) * INNER + h * DH + dq * 4] = res;
}

// ======================= GEGLU elementwise on fused h buffer ====================
// h[row][0..2815]=a, h[row][2816..5631]=g; writes gelu(g)*a into h[row][0..2815].
__global__ void gelu_mul_kernel(bf16* __restrict__ h) {
  const size_t total = (size_t)MROW * FFP / 8;
  for (size_t i = (size_t)blockIdx.x * blockDim.x + threadIdx.x; i < total;
       i += (size_t)gridDim.x * blockDim.x) {
    const size_t row = i / (FFP / 8), c8 = i % (FFP / 8);
    bf16* base = h + row * FF2N + c8 * 8;
    bf16x8 a = *(const bf16x8*)base;
    bf16x8 g = *(const bf16x8*)(base + FFP);
    bf16x8 r;
#pragma unroll
    for (int j = 0; j < 8; ++j) {
      float gv = (float)g[j], av = (float)a[j];
      float ge = 0.5f * gv * (1.0f + erff(gv * 0.70710678118654752f));
      r[j] = (bf16)(ge * av);
    }
    *(bf16x8*)base = r;
  }
}

// ======================= launch ==========================
extern "C" void kernel_launch(void* const* d_in, const int* in_sizes, int n_in,
                              void* d_out, int out_size, void* d_ws, size_t ws_size,
                              hipStream_t stream) {
  (void)in_sizes; (void)n_in; (void)out_size;
  const float* in_x  = (const float*)d_in[0];
  const float* rel   = (const float*)d_in[1];
  const float* ln1g  = (const float*)d_in[2];
  const float* ln1b  = (const float*)d_in[3];
  const float* wq    = (const float*)d_in[4];
  const float* wkv   = (const float*)d_in[5];
  const float* wo    = (const float*)d_in[6];
  const float* ln2g  = (const float*)d_in[7];
  const float* ln2b  = (const float*)d_in[8];
  const float* w1    = (const float*)d_in[9];
  const float* w2    = (const float*)d_in[10];
  const float* lnfg  = (const float*)d_in[11];
  const float* lnfb  = (const float*)d_in[12];
  float* out = (float*)d_out;

  constexpr size_t E_QKV = (size_t)QKVN * DIM;   // fused wq|wkv, [640][1024]
  constexpr size_t E_WO  = (size_t)DIM * INNER;
  constexpr size_t E_W1F = (size_t)FF2N * DIM;   // fused [5632][1024] (a rows then g rows)
  constexpr size_t E_W2  = (size_t)DIM * FFP;
  bf16* wqkvT = (bf16*)d_ws;
  bf16* woT  = wqkvT + NLAY * E_QKV;
  bf16* w1fT = woT  + NLAY * E_WO;
  bf16* w2T  = w1fT + NLAY * E_W1F;
  bf16* xnb  = w2T  + NLAY * E_W2;
  bf16* qkvb = xnb  + (size_t)MROW * DIM;
  bf16* vTb  = qkvb + (size_t)MROW * QKVN;
  bf16* ob   = vTb  + (size_t)NB * 64 * NN;
  bf16* hb   = ob   + (size_t)MROW * INNER;      // fused [4096][5632]
  float* xbuf = (float*)(hb + (size_t)MROW * FF2N);
  float* btab = xbuf + (size_t)MROW * DIM;
  const size_t needed = (size_t)((char*)(btab + NH * NN) - (char*)d_ws);
  if (ws_size < needed) return;  // visible clean failure instead of corruption
  // attn partials overlaid on hb (idle during attention):
  // Opart: 4 splits * 16 bh * 64 d * 2048 q * 4B = 33.6MB; mlbuf 1MB at +36MB (hb is 46MB)
  float* Opart = (float*)hb;
  float* mlbuf = (float*)(hb + (size_t)18 * 1024 * 1024);
  hipMemcpyAsync(xbuf, in_x, (size_t)MROW * DIM * sizeof(float),
                 hipMemcpyDeviceToDevice, stream);
  btab_kernel<<<8, 256, 0, stream>>>(rel, btab);

  const dim3 tb(32, 8);
  conv_tr<<<dim3(16, 32, 6), tb, 0, stream>>>(wq,  (size_t)DIM*INNER, INNER, 0, DIM, INNER,
                                              wqkvT, E_QKV, DIM, 0.125f);  // fold DH^-0.5
  conv_tr<<<dim3(4, 32, 6),  tb, 0, stream>>>(wkv, (size_t)DIM*128, 128, 0, DIM, 128,
                                              wqkvT + (size_t)INNER*DIM, E_QKV, DIM, 1.0f);
  conv_tr<<<dim3(32, 16, 6), tb, 0, stream>>>(wo,  (size_t)INNER*DIM, DIM, 0, INNER, DIM,
                                              woT,  E_WO, INNER, 1.0f);
  conv_tr<<<dim3(88, 32, 6), tb, 0, stream>>>(w1,  (size_t)DIM*2*FF, 2*FF, 0, DIM, FF,
                                              w1fT, E_W1F, DIM, 1.0f);
  conv_tr<<<dim3(88, 32, 6), tb, 0, stream>>>(w1,  (size_t)DIM*2*FF, 2*FF, FF, DIM, FF,
                                              w1fT + (size_t)FFP*DIM, E_W1F, DIM, 1.0f);
  conv_tr<<<dim3(32, 88, 6), tb, 0, stream>>>(w2,  (size_t)FF*DIM, DIM, 0, FF, DIM,
                                              w2T,  E_W2, FFP, 1.0f);

  for (int l = 0; l < NLAY; ++l) {
    ln_kernel<bf16><<<MROW, 256, 0, stream>>>(xbuf, ln1g + l*DIM, ln1b + l*DIM, xnb);
    gemm_bt<0><<<dim3(QKVN/128, MROW/128), 512, 0, stream>>>(xnb, wqkvT + l*E_QKV, DIM, DIM, QKVN, qkvb, nullptr);
    vt_kernel<<<dim3(NN/32, 2, NB), tb, 0, stream>>>(qkvb, vTb);
    attn_kernel<<<dim3((NN/32)*NSPLIT, NH/4, NB), 256, 0, stream>>>(qkvb, vTb, btab, Opart, mlbuf);
    attn_combine<<<AROWS*16/256, 256, 0, stream>>>(Opart, mlbuf, ob);
    gemm_bt<1><<<dim3(DIM/128, MROW/128), 512, 0, stream>>>(ob, woT + l*E_WO, INNER, INNER, DIM, nullptr, xbuf);
    ln_kernel<bf16><<<MROW, 256, 0, stream>>>(xbuf, ln2g + l*DIM, ln2b + l*DIM, xnb);
    gemm_bt<0><<<dim3(FF2N/128, MROW/128), 512, 0, stream>>>(xnb, w1fT + l*E_W1F, DIM, DIM, FF2N, hb, nullptr);
    gelu_mul_kernel<<<2048, 256, 0, stream>>>(hb);
    gemm_bt<1><<<dim3(DIM/128, MROW/128), 512, 0, stream>>>(hb, w2T + l*E_W2, FFP, FF2N, DIM, nullptr, xbuf);
  }
  ln_kernel<float><<<MROW, 256, 0, stream>>>(xbuf, lnfg, lnfb, out);
}

// Round 10
// 1667.772 us; speedup vs baseline: 1.2789x; 1.0431x over previous
//
#include <hip/hip_runtime.h>
#include <cstdint>
#include <cstddef>

using bf16 = __bf16;
typedef __bf16 bf16x8 __attribute__((ext_vector_type(8)));
typedef __bf16 bf16x4 __attribute__((ext_vector_type(4)));
typedef __bf16 bf16x2 __attribute__((ext_vector_type(2)));
typedef float  f32x4  __attribute__((ext_vector_type(4)));
typedef float  f32x16 __attribute__((ext_vector_type(16)));
typedef int    i32x4  __attribute__((ext_vector_type(4)));
typedef float  f32x4u __attribute__((ext_vector_type(4), aligned(4)));  // 4B-aligned vec load

// ---- problem constants ----
constexpr int NB   = 2;      // batch
constexpr int NN   = 2048;   // seq
constexpr int DIM  = 1024;
constexpr int NH   = 8;
constexpr int DH   = 64;
constexpr int INNER= 512;
constexpr int QKVN = 640;    // fused Q(512) + K(64) + V(64) projection width
constexpr int FF   = 2730;
constexpr int FFP  = 2816;   // padded FF (22*128)
constexpr int FF2N = 5632;   // fused a|g FF1 output width (interleaved 32-groups)
constexpr int MROW = NB * NN;   // 4096
constexpr int NLAY = 6;
constexpr int AROWS = NB * NH * NN;  // 32768 attention (b,h,q) rows
constexpr int NSPLIT = 4;            // KV splits

// async global->LDS, 16B per lane; LDS dest is wave-uniform base (+lane*16 by HW)
__device__ __forceinline__ void gload_lds16(const bf16* g, bf16* l) {
  __builtin_amdgcn_global_load_lds((const __attribute__((address_space(1))) void*)g,
                                   (__attribute__((address_space(3))) void*)l,
                                   16, 0, 0);
}

__device__ __forceinline__ int pack_bf16(float lo, float hi_) {
  bf16x2 t; t[0] = (bf16)lo; t[1] = (bf16)hi_;
  return __builtin_bit_cast(int, t);
}

// ======================= bias table ==========================
__global__ void btab_kernel(const float* __restrict__ rel, float* __restrict__ btab) {
  int d = blockIdx.x * 256 + threadIdx.x;
  if (d >= NN) return;
  int bucket;
  if (d < 16) bucket = d;
  else {
    int vl = 16 + (int)(logf((float)d / 16.0f) / logf(8.0f) * 16.0f);
    bucket = vl < 31 ? vl : 31;
  }
  for (int h = 0; h < NH; ++h) btab[h * NN + d] = rel[bucket * NH + h];
}

// ============== weight convert + transpose (+pad, +scale, +row-remap) ==============
// rowOff16 < 0: dst row = i.  rowOff16 >= 0: dst row = ((i>>4)<<5) + rowOff16 + (i&15)
// (interleaves two sources into 32-row groups: a rows at +0, g rows at +16).
__global__ void conv_tr(const float* __restrict__ src, size_t srcLayer, int srcStride,
                        int colOff, int R, int C,
                        bf16* __restrict__ dst, size_t dstLayer, int Tcols, float scale,
                        int rowOff16) {
  __shared__ float tile[32][33];
  const int i0 = blockIdx.x * 32, j0 = blockIdx.y * 32, z = blockIdx.z;
  const float* s = src + (size_t)z * srcLayer;
  bf16* d = dst + (size_t)z * dstLayer;
  const int tx = threadIdx.x, ty = threadIdx.y;
#pragma unroll
  for (int k = 0; k < 4; ++k) {
    int j = j0 + ty + k * 8;
    int i = i0 + tx;
    float v = 0.0f;
    if (j < R && i < C) v = s[(size_t)j * srcStride + colOff + i] * scale;
    tile[ty + k * 8][tx] = v;
  }
  __syncthreads();
#pragma unroll
  for (int k = 0; k < 4; ++k) {
    int i = i0 + ty + k * 8;   // logical dst row
    int j = j0 + tx;           // dst col
    int dr = (rowOff16 >= 0) ? (((i >> 4) << 5) + rowOff16 + (i & 15)) : i;
    d[(size_t)dr * Tcols + j] = (bf16)tile[tx][ty + k * 8];
  }
}

// ======================= LayerNorm ==========================
template <typename OUT>
__global__ void ln_kernel(const float* __restrict__ X, const float* __restrict__ G,
                          const float* __restrict__ Bt, OUT* __restrict__ out) {
  __shared__ float red[8];
  const int row = blockIdx.x, t = threadIdx.x;
  const float* xr = X + (size_t)row * DIM;
  float4 v = *(const float4*)(xr + t * 4);
  float s  = v.x + v.y + v.z + v.w;
  float s2 = v.x * v.x + v.y * v.y + v.z * v.z + v.w * v.w;
#pragma unroll
  for (int o = 1; o < 64; o <<= 1) { s += __shfl_xor(s, o); s2 += __shfl_xor(s2, o); }
  if ((t & 63) == 0) { red[t >> 6] = s; red[4 + (t >> 6)] = s2; }
  __syncthreads();
  float S  = red[0] + red[1] + red[2] + red[3];
  float S2 = red[4] + red[5] + red[6] + red[7];
  const float inv = 1.0f / (float)DIM;
  float mu = S * inv;
  float var = S2 * inv - mu * mu;
  float rstd = rsqrtf(var + 1e-5f);
  float4 g  = *(const float4*)(G + t * 4);
  float4 bb = *(const float4*)(Bt + t * 4);
  OUT* orow = out + (size_t)row * DIM + t * 4;
  orow[0] = (OUT)((v.x - mu) * rstd * g.x + bb.x);
  orow[1] = (OUT)((v.y - mu) * rstd * g.y + bb.y);
  orow[2] = (OUT)((v.z - mu) * rstd * g.z + bb.z);
  orow[3] = (OUT)((v.w - mu) * rstd * g.w + bb.w);
}

// ======================= GEMM: C[M,N] = A[M,K] @ B^T[N,K] ==========================
// r6-exact core (best measured): 128x128 tile, BK=64, 8 waves (2Mx4N, 64x32 each),
// double-buffered LDS (64KB -> 2 blocks/CU), prefetch distance 1, 2 barriers per
// K-step. Swizzle: pre-swizzled GLOBAL source col + linear LDS dest + XOR on read
// (bank-conflict 0, verified). XCD block swizzle (all grids %8==0).
// MODE 0: store bf16 C (stride N).  MODE 1: Xr += acc (fp32 residual, stride N).
// MODE 2: GEGLU epilogue -- B rows are interleaved 32-groups (a at +0..15, g at
// +16..31), so acc[m][0]=a_j, acc[m][1]=g_j for the SAME lane; writes
// gelu(g)*a as bf16 to compact Cb with row stride N (pass N=FFP), col j=(n0+wn)/2+cc.
template <int MODE>
__launch_bounds__(512)
__global__ void gemm_bt(const bf16* __restrict__ A, const bf16* __restrict__ B,
                        int K, int lda, int N, bf16* __restrict__ Cb, float* __restrict__ Xr) {
  __shared__ __align__(16) bf16 As[2][128 * 64];
  __shared__ __align__(16) bf16 Bs[2][128 * 64];
  const int tid = threadIdx.x;
  const int lane = tid & 63, wave = tid >> 6;
  const int gx = gridDim.x, gy = gridDim.y;
  const int nwg = gx * gy;
  const int orig = blockIdx.y * gx + blockIdx.x;
  const int wgid = (orig & 7) * (nwg >> 3) + (orig >> 3);  // XCD swizzle (nwg%8==0)
  const int m0 = (wgid % gy) * 128;   // M fastest within XCD chunk -> B-panel L2 reuse
  const int n0 = (wgid / gy) * 128;
  const int wm = (wave >> 2) * 64, wn = (wave & 3) * 32;
  const int fr = lane & 15, fg8 = (lane >> 4) * 8;
  const int frl8 = (fr & 7) * 8;           // read-side swizzle XOR
  const int rL = lane >> 3;                // staging row within 8-row group
  const int cS = ((lane & 7) ^ rL) * 8;    // pre-swizzled global source col
  const bf16* aB = A + (size_t)(m0 + wave * 8 + rL) * lda + cS;
  const bf16* bB = B + (size_t)(n0 + wave * 8 + rL) * K + cS;
  f32x4 acc[4][2] = {};

  auto STAGE = [&](int buf, int kt) {
#pragma unroll
    for (int r = 0; r < 2; ++r) {
      gload_lds16(aB + (size_t)(r * 64) * lda + kt, &As[buf][(r * 8 + wave) * 512]);
      gload_lds16(bB + (size_t)(r * 64) * K + kt, &Bs[buf][(r * 8 + wave) * 512]);
    }
  };

  STAGE(0, 0);
  const int nt = K >> 6;
  int cur = 0;
  for (int t = 0; t < nt; ++t) {
    asm volatile("s_waitcnt vmcnt(0)" ::: "memory");  // buf[cur] DMA (this wave) done
    __builtin_amdgcn_s_barrier();                     // all waves' DMA done
    __builtin_amdgcn_sched_barrier(0);
    if (t + 1 < nt) STAGE(cur ^ 1, (t + 1) * 64);     // in flight across the compute
#pragma unroll
    for (int kk = 0; kk < 64; kk += 32) {
      bf16x8 af[4], bfr[2];
#pragma unroll
      for (int m = 0; m < 4; ++m)
        af[m] = *(const bf16x8*)&As[cur][(wm + m * 16 + fr) * 64 + ((kk + fg8) ^ frl8)];
#pragma unroll
      for (int n = 0; n < 2; ++n)
        bfr[n] = *(const bf16x8*)&Bs[cur][(wn + n * 16 + fr) * 64 + ((kk + fg8) ^ frl8)];
#pragma unroll
      for (int m = 0; m < 4; ++m)
#pragma unroll
        for (int n = 0; n < 2; ++n)
          acc[m][n] = __builtin_amdgcn_mfma_f32_16x16x32_bf16(af[m], bfr[n], acc[m][n], 0, 0, 0);
    }
    __builtin_amdgcn_sched_barrier(0);
    __builtin_amdgcn_s_barrier();                     // cur fully read; next STAGE may overwrite
    cur ^= 1;
  }
  const int cc = lane & 15, cg = (lane >> 4) * 4;
  if (MODE == 2) {
    const int jcol = (n0 + wn) / 2 + cc;   // pair index (n0+wn divisible by 32)
#pragma unroll
    for (int m = 0; m < 4; ++m) {
#pragma unroll
      for (int r = 0; r < 4; ++r) {
        const int row = m0 + wm + m * 16 + cg + r;
        const float av = acc[m][0][r], gv = acc[m][1][r];
        const float ge = 0.5f * gv * (1.0f + erff(gv * 0.70710678118654752f)) * av;
        Cb[(size_t)row * N + jcol] = (bf16)ge;
      }
    }
  } else {
#pragma unroll
    for (int m = 0; m < 4; ++m) {
#pragma unroll
      for (int n = 0; n < 2; ++n) {
        const int col = n0 + wn + n * 16 + cc;
#pragma unroll
        for (int r = 0; r < 4; ++r) {
          const int row = m0 + wm + m * 16 + cg + r;
          const size_t idx = (size_t)row * N + col;
          if (MODE == 0) Cb[idx] = (bf16)acc[m][n][r];
          else           Xr[idx] += acc[m][n][r];
        }
      }
    }
  }
}

// ======================= V transpose: VT[b][dh][n] = QKV[b*NN+n][576+dh] ==========
__global__ void vt_kernel(const bf16* __restrict__ QKV, bf16* __restrict__ VT) {
  __shared__ bf16 t[32][33];
  const int n0 = blockIdx.x * 32, d0 = blockIdx.y * 32, b = blockIdx.z;
  const int tx = threadIdx.x, ty = threadIdx.y;
#pragma unroll
  for (int k = 0; k < 4; ++k) {
    int n = n0 + ty + k * 8;
    t[ty + k * 8][tx] = QKV[(size_t)(b * NN + n) * QKVN + 576 + d0 + tx];
  }
  __syncthreads();
#pragma unroll
  for (int k = 0; k < 4; ++k) {
    int dh = d0 + ty + k * 8;
    VT[(size_t)(b * 64 + dh) * NN + n0 + tx] = t[tx][ty + k * 8];
  }
}

// ======================= attention: 32x32 MFMA, in-register softmax ==============
// 4 waves/block = 4 heads (MQA: K/V shared -> L1 reuse), no barriers, no LDS.
// NSPLIT=4 KV splits -> 1024 blocks = 4 waves/SIMD co-resident. Partials in
// q-major layout Opart[split][bh][q][64] so the combine reads are coalesced
// (each lane owns one 256B row here; 2x write amp vs 16x read amp before).
__launch_bounds__(256)
__global__ void attn_kernel(const bf16* __restrict__ QKV, const bf16* __restrict__ VT,
                            const float* __restrict__ btab,
                            float* __restrict__ Opart, float* __restrict__ mlbuf) {
  const int tid = threadIdx.x;
  const int lane = tid & 63, wv = tid >> 6;
  const int split = blockIdx.x & (NSPLIT - 1);
  const int qt = (NN / 32 - 1) - (blockIdx.x / NSPLIT);   // longest-first
  const int h = blockIdx.y * 4 + wv, b = blockIdx.z;
  const int q0 = qt * 32;
  const int qc = lane & 31;        // q col (also A-operand row index, also V^T d row)
  const int hid = lane >> 5;
  const int h8 = hid * 8;
  const int kv_full = q0 + 32;
  // distribute 32-row tiles among NSPLIT splits
  const int nt32 = kv_full >> 5;
  const int base = nt32 >> 2, rem = nt32 & 3;
  const int cnt = base + (split < rem ? 1 : 0);
  const int startT = split * base + (split < rem ? split : rem);
  const int lo = startT * 32;
  const int kend = lo + cnt * 32;
  const size_t obase = ((size_t)(split * NB * NH) + b * NH + h) * NN;  // q-row base
  const int Rbase = (b * NH + h) * NN + q0;
  float* prow = Opart + (obase + q0 + qc) * 64;
  if (cnt == 0) {   // empty split: zero partial block, weight 0 in combine
#pragma unroll
    for (int dd = 0; dd < 32; ++dd) prow[dd * 2 + hid] = 0.0f;
    if (hid == 0)
      ((float2*)mlbuf)[(size_t)split * AROWS + Rbase + qc] = make_float2(-1e30f, 0.0f);
    return;
  }
  const float* bt = btab + h * NN;
  bf16x8 qf[4];
#pragma unroll
  for (int ks = 0; ks < 4; ++ks)
    qf[ks] = *(const bf16x8*)&QKV[(size_t)(b * NN + q0 + qc) * QKVN + h * DH + ks * 16 + h8];

  f32x16 Oacc0 = {}, Oacc1 = {};
  float m_run = -1e30f, l_run = 0.0f;
  int kv0 = lo;

  while (kv0 < kend) {
    const bool interior = (kv0 + 32 <= q0);
    bf16x8 kf[4];
#pragma unroll
    for (int ks = 0; ks < 4; ++ks)
      kf[ks] = *(const bf16x8*)&QKV[(size_t)(b * NN + kv0 + qc) * QKVN + 512 + ks * 16 + h8];
    bf16x8 vf[2][2];
#pragma unroll
    for (int dblk = 0; dblk < 2; ++dblk)
#pragma unroll
      for (int ks2 = 0; ks2 < 2; ++ks2)
        vf[dblk][ks2] = *(const bf16x8*)&VT[(size_t)(b * 64 + dblk * 32 + qc) * NN + kv0 + ks2 * 16 + h8];
    __builtin_amdgcn_s_setprio(1);
    f32x16 S = {};
#pragma unroll
    for (int ks = 0; ks < 4; ++ks)
      S = __builtin_amdgcn_mfma_f32_32x32x16_bf16(kf[ks], qf[ks], S, 0, 0, 0);
    __builtin_amdgcn_s_setprio(0);
    float sv[16];
    float mx = -1e30f;
    if (interior) {
      f32x4 bv[4];
#pragma unroll
      for (int g = 0; g < 4; ++g)
        bv[g] = *(const f32x4u*)(bt + (q0 + qc - kv0 - 8 * g - 4 * hid - 3));
#pragma unroll
      for (int g = 0; g < 4; ++g)
#pragma unroll
        for (int e = 0; e < 4; ++e) {
          const float val = S[g * 4 + e] + bv[g][3 - e];
          sv[g * 4 + e] = val;
          mx = fmaxf(mx, val);
        }
    } else {
#pragma unroll
      for (int r = 0; r < 16; ++r) {
        const int kvr = (r & 3) + 8 * (r >> 2) + 4 * hid;
        const int d = (q0 + qc) - (kv0 + kvr);
        const int dc = d > 0 ? d : 0;
        float val = S[r] + bt[dc];
        if (d < 0) val = -1e30f;
        sv[r] = val;
        mx = fmaxf(mx, val);
      }
    }
    if (!__all(mx <= m_run + 8.0f)) {
      mx = fmaxf(mx, __shfl_xor(mx, 32));
      const float m_new = fmaxf(m_run, mx);
      const float sc = __expf(m_run - m_new);
      l_run *= sc;
#pragma unroll
      for (int r = 0; r < 16; ++r) { Oacc0[r] *= sc; Oacc1[r] *= sc; }
      m_run = m_new;
    }
    float csum = 0.0f;
#pragma unroll
    for (int r = 0; r < 16; ++r) { sv[r] = __expf(sv[r] - m_run); csum += sv[r]; }
    csum += __shfl_xor(csum, 32);
    l_run += csum;
    int w[8];
#pragma unroll
    for (int g = 0; g < 4; ++g) {
      w[2 * g]     = pack_bf16(sv[4 * g],     sv[4 * g + 1]);
      w[2 * g + 1] = pack_bf16(sv[4 * g + 2], sv[4 * g + 3]);
    }
    bf16x8 pfrag[2];
#pragma unroll
    for (int ks2 = 0; ks2 < 2; ++ks2) {
      const int a  = w[4 * ks2],     bb = w[4 * ks2 + 1];
      const int c  = w[4 * ks2 + 2], dd = w[4 * ks2 + 3];
      const int s0 = hid ? a : c,    s1 = hid ? bb : dd;
      const int r0 = __shfl_xor(s0, 32);
      const int r1 = __shfl_xor(s1, 32);
      i32x4 fw;
      fw[0] = hid ? r0 : a;
      fw[1] = hid ? r1 : bb;
      fw[2] = hid ? c  : r0;
      fw[3] = hid ? dd : r1;
      pfrag[ks2] = __builtin_bit_cast(bf16x8, fw);
    }
    __builtin_amdgcn_s_setprio(1);
#pragma unroll
    for (int ks2 = 0; ks2 < 2; ++ks2) {
      Oacc0 = __builtin_amdgcn_mfma_f32_32x32x16_bf16(vf[0][ks2], pfrag[ks2], Oacc0, 0, 0, 0);
      Oacc1 = __builtin_amdgcn_mfma_f32_32x32x16_bf16(vf[1][ks2], pfrag[ks2], Oacc1, 0, 0, 0);
    }
    __builtin_amdgcn_s_setprio(0);
    kv0 += 32;
  }
#pragma unroll
  for (int r = 0; r < 16; ++r) {
    const int dl = (r & 3) + 8 * (r >> 2) + 4 * hid;
    prow[dl]      = Oacc0[r];
    prow[32 + dl] = Oacc1[r];
  }
  if (hid == 0)
    ((float2*)mlbuf)[(size_t)split * AROWS + Rbase + qc] = make_float2(m_run, l_run);
}

// ======================= combine split-KV partials -> O (bf16) =================
// Opart layout: [split][bh][NN q][64 d] f32 (q-major). Thread: dq fastest -> fully
// coalesced f32x4 reads and 128B O-row writes per 16-thread group.
__global__ void attn_combine(const float* __restrict__ Opart, const float* __restrict__ mlbuf,
                             bf16* __restrict__ O) {
  const int gtid = blockIdx.x * 256 + threadIdx.x;   // NB*NH*NN*16 threads
  const int dq = gtid & 15;
  const int q  = (gtid >> 4) & (NN - 1);
  const int bh = gtid >> 15;                          // b*NH + h
  const int R = bh * NN + q;
  float2 ml[NSPLIT];
  float m = -1e30f;
#pragma unroll
  for (int s = 0; s < NSPLIT; ++s) {
    ml[s] = ((const float2*)mlbuf)[(size_t)s * AROWS + R];
    m = fmaxf(m, ml[s].x);
  }
  float w[NSPLIT];
  float denom = 0.0f;
#pragma unroll
  for (int s = 0; s < NSPLIT; ++s) {
    w[s] = __expf(ml[s].x - m);
    denom += ml[s].y * w[s];
  }
  const float inv = 1.0f / denom;
  float o[4] = {};
#pragma unroll
  for (int s = 0; s < NSPLIT; ++s) {
    const f32x4 v = *(const f32x4*)(Opart + ((size_t)(s * NB * NH + bh) * NN + q) * 64 + dq * 4);
#pragma unroll
    for (int j = 0; j < 4; ++j) o[j] += v[j] * w[s];
  }
  bf16x4 res;
#pragma unroll
  for (int j = 0; j < 4; ++j) res[j] = (bf16)(o[j] * inv);
  const int h = bh & (NH - 1), b = bh >> 3;
  *(bf16x4*)&O[(size_t)(b * NN + q) * INNER + h * DH + dq * 4] = res;
}

// ======================= launch ==========================
extern "C" void kernel_launch(void* const* d_in, const int* in_sizes, int n_in,
                              void* d_out, int out_size, void* d_ws, size_t ws_size,
                              hipStream_t stream) {
  (void)in_sizes; (void)n_in; (void)out_size;
  const float* in_x  = (const float*)d_in[0];
  const float* rel   = (const float*)d_in[1];
  const float* ln1g  = (const float*)d_in[2];
  const float* ln1b  = (const float*)d_in[3];
  const float* wq    = (const float*)d_in[4];
  const float* wkv   = (const float*)d_in[5];
  const float* wo    = (const float*)d_in[6];
  const float* ln2g  = (const float*)d_in[7];
  const float* ln2b  = (const float*)d_in[8];
  const float* w1    = (const float*)d_in[9];
  const float* w2    = (const float*)d_in[10];
  const float* lnfg  = (const float*)d_in[11];
  const float* lnfb  = (const float*)d_in[12];
  float* out = (float*)d_out;

  constexpr size_t E_QKV = (size_t)QKVN * DIM;   // fused wq|wkv, [640][1024]
  constexpr size_t E_WO  = (size_t)DIM * INNER;
  constexpr size_t E_W1F = (size_t)FF2N * DIM;   // interleaved a/g [5632][1024]
  constexpr size_t E_W2  = (size_t)DIM * FFP;
  bf16* wqkvT = (bf16*)d_ws;
  bf16* woT  = wqkvT + NLAY * E_QKV;
  bf16* w1fT = woT  + NLAY * E_WO;
  bf16* w2T  = w1fT + NLAY * E_W1F;
  bf16* xnb  = w2T  + NLAY * E_W2;
  bf16* qkvb = xnb  + (size_t)MROW * DIM;
  bf16* vTb  = qkvb + (size_t)MROW * QKVN;
  bf16* ob   = vTb  + (size_t)NB * 64 * NN;
  bf16* hb   = ob   + (size_t)MROW * INNER;      // FF phase: compact [4096][FFP]
  float* xbuf = (float*)(hb + (size_t)MROW * FF2N);
  float* btab = xbuf + (size_t)MROW * DIM;
  const size_t needed = (size_t)((char*)(btab + NH * NN) - (char*)d_ws);
  if (ws_size < needed) return;  // visible clean failure instead of corruption
  // attn partials overlaid on hb (FF phase and attn phase are disjoint in time):
  // Opart: 4 splits * 16 bh * 2048 q * 64 d * 4B = 33.6MB; mlbuf 1MB at +36MB (hb is 46MB)
  float* Opart = (float*)hb;
  float* mlbuf = (float*)(hb + (size_t)18 * 1024 * 1024);
  hipMemcpyAsync(xbuf, in_x, (size_t)MROW * DIM * sizeof(float),
                 hipMemcpyDeviceToDevice, stream);
  btab_kernel<<<8, 256, 0, stream>>>(rel, btab);

  const dim3 tb(32, 8);
  conv_tr<<<dim3(16, 32, 6), tb, 0, stream>>>(wq,  (size_t)DIM*INNER, INNER, 0, DIM, INNER,
                                              wqkvT, E_QKV, DIM, 0.125f, -1);  // fold DH^-0.5
  conv_tr<<<dim3(4, 32, 6),  tb, 0, stream>>>(wkv, (size_t)DIM*128, 128, 0, DIM, 128,
                                              wqkvT + (size_t)INNER*DIM, E_QKV, DIM, 1.0f, -1);
  conv_tr<<<dim3(32, 16, 6), tb, 0, stream>>>(wo,  (size_t)INNER*DIM, DIM, 0, INNER, DIM,
                                              woT,  E_WO, INNER, 1.0f, -1);
  conv_tr<<<dim3(88, 32, 6), tb, 0, stream>>>(w1,  (size_t)DIM*2*FF, 2*FF, 0, DIM, FF,
                                              w1fT, E_W1F, DIM, 1.0f, 0);    // a rows -> +0
  conv_tr<<<dim3(88, 32, 6), tb, 0, stream>>>(w1,  (size_t)DIM*2*FF, 2*FF, FF, DIM, FF,
                                              w1fT, E_W1F, DIM, 1.0f, 16);   // g rows -> +16
  conv_tr<<<dim3(32, 88, 6), tb, 0, stream>>>(w2,  (size_t)FF*DIM, DIM, 0, FF, DIM,
                                              w2T,  E_W2, FFP, 1.0f, -1);

  for (int l = 0; l < NLAY; ++l) {
    ln_kernel<bf16><<<MROW, 256, 0, stream>>>(xbuf, ln1g + l*DIM, ln1b + l*DIM, xnb);
    gemm_bt<0><<<dim3(QKVN/128, MROW/128), 512, 0, stream>>>(xnb, wqkvT + l*E_QKV, DIM, DIM, QKVN, qkvb, nullptr);
    vt_kernel<<<dim3(NN/32, 2, NB), tb, 0, stream>>>(qkvb, vTb);
    attn_kernel<<<dim3((NN/32)*NSPLIT, NH/4, NB), 256, 0, stream>>>(qkvb, vTb, btab, Opart, mlbuf);
    attn_combine<<<AROWS*16/256, 256, 0, stream>>>(Opart, mlbuf, ob);
    gemm_bt<1><<<dim3(DIM/128, MROW/128), 512, 0, stream>>>(ob, woT + l*E_WO, INNER, INNER, DIM, nullptr, xbuf);
    ln_kernel<bf16><<<MROW, 256, 0, stream>>>(xbuf, ln2g + l*DIM, ln2b + l*DIM, xnb);
    gemm_bt<2><<<dim3(FF2N/128, MROW/128), 512, 0, stream>>>(xnb, w1fT + l*E_W1F, DIM, DIM, FFP, hb, nullptr);
    gemm_bt<1><<<dim3(DIM/128, MROW/128), 512, 0, stream>>>(hb, w2T + l*E_W2, FFP, FFP, DIM, nullptr, xbuf);
  }
  ln_kernel<float><<<MROW, 256, 0, stream>>>(xbuf, lnfg, lnfb, out);
}

// Round 11
// 1604.467 us; speedup vs baseline: 1.3294x; 1.0395x over previous
//
#include <hip/hip_runtime.h>
#include <cstdint>
#include <cstddef>

using bf16 = __bf16;
typedef __bf16 bf16x8 __attribute__((ext_vector_type(8)));
typedef __bf16 bf16x4 __attribute__((ext_vector_type(4)));
typedef __bf16 bf16x2 __attribute__((ext_vector_type(2)));
typedef float  f32x4  __attribute__((ext_vector_type(4)));
typedef float  f32x16 __attribute__((ext_vector_type(16)));
typedef int    i32x4  __attribute__((ext_vector_type(4)));
typedef float  f32x4u __attribute__((ext_vector_type(4), aligned(4)));  // 4B-aligned vec load

// ---- problem constants ----
constexpr int NB   = 2;      // batch
constexpr int NN   = 2048;   // seq
constexpr int DIM  = 1024;
constexpr int NH   = 8;
constexpr int DH   = 64;
constexpr int INNER= 512;
constexpr int QKVN = 640;    // fused Q(512) + K(64) + V(64) projection width
constexpr int FF   = 2730;
constexpr int FFP  = 2816;   // padded FF (22*128)
constexpr int FF2N = 5632;   // fused a|g FF1 output width (interleaved 32-groups)
constexpr int MROW = NB * NN;   // 4096
constexpr int NLAY = 6;
constexpr int AROWS = NB * NH * NN;  // 32768 attention (b,h,q) rows
constexpr int NSPLIT = 4;            // KV splits

// async global->LDS, 16B per lane; LDS dest is wave-uniform base (+lane*16 by HW)
__device__ __forceinline__ void gload_lds16(const bf16* g, bf16* l) {
  __builtin_amdgcn_global_load_lds((const __attribute__((address_space(1))) void*)g,
                                   (__attribute__((address_space(3))) void*)l,
                                   16, 0, 0);
}

__device__ __forceinline__ int pack_bf16(float lo, float hi_) {
  bf16x2 t; t[0] = (bf16)lo; t[1] = (bf16)hi_;
  return __builtin_bit_cast(int, t);
}

// ======================= bias table ==========================
__global__ void btab_kernel(const float* __restrict__ rel, float* __restrict__ btab) {
  int d = blockIdx.x * 256 + threadIdx.x;
  if (d >= NN) return;
  int bucket;
  if (d < 16) bucket = d;
  else {
    int vl = 16 + (int)(logf((float)d / 16.0f) / logf(8.0f) * 16.0f);
    bucket = vl < 31 ? vl : 31;
  }
  for (int h = 0; h < NH; ++h) btab[h * NN + d] = rel[bucket * NH + h];
}

// ============== weight convert + transpose (+pad, +scale, +row-remap) ==============
// rowOff16 < 0: dst row = i.  rowOff16 >= 0: dst row = ((i>>4)<<5) + rowOff16 + (i&15)
// (interleaves two sources into 32-row groups: a rows at +0, g rows at +16).
__global__ void conv_tr(const float* __restrict__ src, size_t srcLayer, int srcStride,
                        int colOff, int R, int C,
                        bf16* __restrict__ dst, size_t dstLayer, int Tcols, float scale,
                        int rowOff16) {
  __shared__ float tile[32][33];
  const int i0 = blockIdx.x * 32, j0 = blockIdx.y * 32, z = blockIdx.z;
  const float* s = src + (size_t)z * srcLayer;
  bf16* d = dst + (size_t)z * dstLayer;
  const int tx = threadIdx.x, ty = threadIdx.y;
#pragma unroll
  for (int k = 0; k < 4; ++k) {
    int j = j0 + ty + k * 8;
    int i = i0 + tx;
    float v = 0.0f;
    if (j < R && i < C) v = s[(size_t)j * srcStride + colOff + i] * scale;
    tile[ty + k * 8][tx] = v;
  }
  __syncthreads();
#pragma unroll
  for (int k = 0; k < 4; ++k) {
    int i = i0 + ty + k * 8;   // logical dst row
    int j = j0 + tx;           // dst col
    int dr = (rowOff16 >= 0) ? (((i >> 4) << 5) + rowOff16 + (i & 15)) : i;
    d[(size_t)dr * Tcols + j] = (bf16)tile[tx][ty + k * 8];
  }
}

// ======================= LayerNorm ==========================
template <typename OUT>
__global__ void ln_kernel(const float* __restrict__ X, const float* __restrict__ G,
                          const float* __restrict__ Bt, OUT* __restrict__ out) {
  __shared__ float red[8];
  const int row = blockIdx.x, t = threadIdx.x;
  const float* xr = X + (size_t)row * DIM;
  float4 v = *(const float4*)(xr + t * 4);
  float s  = v.x + v.y + v.z + v.w;
  float s2 = v.x * v.x + v.y * v.y + v.z * v.z + v.w * v.w;
#pragma unroll
  for (int o = 1; o < 64; o <<= 1) { s += __shfl_xor(s, o); s2 += __shfl_xor(s2, o); }
  if ((t & 63) == 0) { red[t >> 6] = s; red[4 + (t >> 6)] = s2; }
  __syncthreads();
  float S  = red[0] + red[1] + red[2] + red[3];
  float S2 = red[4] + red[5] + red[6] + red[7];
  const float inv = 1.0f / (float)DIM;
  float mu = S * inv;
  float var = S2 * inv - mu * mu;
  float rstd = rsqrtf(var + 1e-5f);
  float4 g  = *(const float4*)(G + t * 4);
  float4 bb = *(const float4*)(Bt + t * 4);
  OUT* orow = out + (size_t)row * DIM + t * 4;
  orow[0] = (OUT)((v.x - mu) * rstd * g.x + bb.x);
  orow[1] = (OUT)((v.y - mu) * rstd * g.y + bb.y);
  orow[2] = (OUT)((v.z - mu) * rstd * g.z + bb.z);
  orow[3] = (OUT)((v.w - mu) * rstd * g.w + bb.w);
}

// ======================= GEMM (r6 core, for N<=1024 shapes) ==========================
// 128x128 tile, BK=64, 8 waves (2Mx4N, 64x32 each), double-buffered LDS (64KB),
// prefetch distance 1, 2 barriers/K-step. Used for QKV/WO/FF2 (small grids, 2/CU).
// MODE 0: store bf16 C. MODE 1: Xr += acc (fp32 residual).
template <int MODE>
__launch_bounds__(512)
__global__ void gemm_bt(const bf16* __restrict__ A, const bf16* __restrict__ B,
                        int K, int lda, int N, bf16* __restrict__ Cb, float* __restrict__ Xr) {
  __shared__ __align__(16) bf16 As[2][128 * 64];
  __shared__ __align__(16) bf16 Bs[2][128 * 64];
  const int tid = threadIdx.x;
  const int lane = tid & 63, wave = tid >> 6;
  const int gx = gridDim.x, gy = gridDim.y;
  const int nwg = gx * gy;
  const int orig = blockIdx.y * gx + blockIdx.x;
  const int wgid = (orig & 7) * (nwg >> 3) + (orig >> 3);  // XCD swizzle (nwg%8==0)
  const int m0 = (wgid % gy) * 128;   // M fastest within XCD chunk -> B-panel L2 reuse
  const int n0 = (wgid / gy) * 128;
  const int wm = (wave >> 2) * 64, wn = (wave & 3) * 32;
  const int fr = lane & 15, fg8 = (lane >> 4) * 8;
  const int frl8 = (fr & 7) * 8;           // read-side swizzle XOR
  const int rL = lane >> 3;                // staging row within 8-row group
  const int cS = ((lane & 7) ^ rL) * 8;    // pre-swizzled global source col
  const bf16* aB = A + (size_t)(m0 + wave * 8 + rL) * lda + cS;
  const bf16* bB = B + (size_t)(n0 + wave * 8 + rL) * K + cS;
  f32x4 acc[4][2] = {};

  auto STAGE = [&](int buf, int kt) {
#pragma unroll
    for (int r = 0; r < 2; ++r) {
      gload_lds16(aB + (size_t)(r * 64) * lda + kt, &As[buf][(r * 8 + wave) * 512]);
      gload_lds16(bB + (size_t)(r * 64) * K + kt, &Bs[buf][(r * 8 + wave) * 512]);
    }
  };

  STAGE(0, 0);
  const int nt = K >> 6;
  int cur = 0;
  for (int t = 0; t < nt; ++t) {
    asm volatile("s_waitcnt vmcnt(0)" ::: "memory");  // buf[cur] DMA (this wave) done
    __builtin_amdgcn_s_barrier();                     // all waves' DMA done
    __builtin_amdgcn_sched_barrier(0);
    if (t + 1 < nt) STAGE(cur ^ 1, (t + 1) * 64);     // in flight across the compute
#pragma unroll
    for (int kk = 0; kk < 64; kk += 32) {
      bf16x8 af[4], bfr[2];
#pragma unroll
      for (int m = 0; m < 4; ++m)
        af[m] = *(const bf16x8*)&As[cur][(wm + m * 16 + fr) * 64 + ((kk + fg8) ^ frl8)];
#pragma unroll
      for (int n = 0; n < 2; ++n)
        bfr[n] = *(const bf16x8*)&Bs[cur][(wn + n * 16 + fr) * 64 + ((kk + fg8) ^ frl8)];
#pragma unroll
      for (int m = 0; m < 4; ++m)
#pragma unroll
        for (int n = 0; n < 2; ++n)
          acc[m][n] = __builtin_amdgcn_mfma_f32_16x16x32_bf16(af[m], bfr[n], acc[m][n], 0, 0, 0);
    }
    __builtin_amdgcn_sched_barrier(0);
    __builtin_amdgcn_s_barrier();                     // cur fully read; next STAGE may overwrite
    cur ^= 1;
  }
  const int cc = lane & 15, cg = (lane >> 4) * 4;
#pragma unroll
  for (int m = 0; m < 4; ++m) {
#pragma unroll
    for (int n = 0; n < 2; ++n) {
      const int col = n0 + wn + n * 16 + cc;
#pragma unroll
      for (int r = 0; r < 4; ++r) {
        const int row = m0 + wm + m * 16 + cg + r;
        const size_t idx = (size_t)row * N + col;
        if (MODE == 0) Cb[idx] = (bf16)acc[m][n][r];
        else           Xr[idx] += acc[m][n][r];
      }
    }
  }
}

// ======================= GEMM m97-structure (for FF1: large grid) ==================
// 128x128 tile, BK=64, 4 waves (2x2, 64x64 each, 4x4 acc), SINGLE 32KB LDS buffer,
// sync/stage/sync/compute. 32KB LDS + ~4 waves/SIMD VGPR -> 3-4 co-resident
// blocks/CU whose wave overlap hides the stage drain (m114/m103: 912 TF measured).
// Source-side swizzle (conflict-free ds_read) + XCD swizzle kept.
// MODE 2: GEGLU epilogue (B rows interleaved 32-groups: a@+0..15, g@+16..31);
// writes gelu(g)*a compact with row stride N (pass N=FFP), cols (n0+wn)/2 + p*16 + cc.
template <int MODE>
__launch_bounds__(256)
__global__ void gemm97(const bf16* __restrict__ A, const bf16* __restrict__ B,
                       int K, int lda, int N, bf16* __restrict__ Cb, float* __restrict__ Xr) {
  __shared__ __align__(16) bf16 As[128 * 64];
  __shared__ __align__(16) bf16 Bs[128 * 64];
  const int tid = threadIdx.x;
  const int lane = tid & 63, wave = tid >> 6;
  const int gx = gridDim.x, gy = gridDim.y;
  const int nwg = gx * gy;
  const int orig = blockIdx.y * gx + blockIdx.x;
  const int wgid = (orig & 7) * (nwg >> 3) + (orig >> 3);  // XCD swizzle (nwg%8==0)
  const int m0 = (wgid % gy) * 128;
  const int n0 = (wgid / gy) * 128;
  const int wm = (wave >> 1) * 64, wn = (wave & 1) * 64;
  const int fr = lane & 15, fg8 = (lane >> 4) * 8;
  const int frl8 = (fr & 7) * 8;
  const int rL = lane >> 3;
  const int cS = ((lane & 7) ^ rL) * 8;
  const bf16* aB = A + (size_t)(m0 + wave * 8 + rL) * lda + cS;
  const bf16* bB = B + (size_t)(n0 + wave * 8 + rL) * K + cS;
  f32x4 acc[4][4] = {};

  for (int kt = 0; kt < K; kt += 64) {
    __syncthreads();   // previous compute done reading LDS
#pragma unroll
    for (int r = 0; r < 4; ++r) {
      gload_lds16(aB + (size_t)(r * 32) * lda + kt, &As[(r * 4 + wave) * 512]);
      gload_lds16(bB + (size_t)(r * 32) * K + kt, &Bs[(r * 4 + wave) * 512]);
    }
    __syncthreads();   // drains vmcnt(0): DMA complete (compiler-inserted)
#pragma unroll
    for (int kk = 0; kk < 64; kk += 32) {
      bf16x8 af[4], bfr[4];
#pragma unroll
      for (int m = 0; m < 4; ++m)
        af[m] = *(const bf16x8*)&As[(wm + m * 16 + fr) * 64 + ((kk + fg8) ^ frl8)];
#pragma unroll
      for (int n = 0; n < 4; ++n)
        bfr[n] = *(const bf16x8*)&Bs[(wn + n * 16 + fr) * 64 + ((kk + fg8) ^ frl8)];
#pragma unroll
      for (int m = 0; m < 4; ++m)
#pragma unroll
        for (int n = 0; n < 4; ++n)
          acc[m][n] = __builtin_amdgcn_mfma_f32_16x16x32_bf16(af[m], bfr[n], acc[m][n], 0, 0, 0);
    }
  }
  const int cc = lane & 15, cg = (lane >> 4) * 4;
  if (MODE == 2) {
    const int jbase = (n0 + wn) / 2 + cc;
#pragma unroll
    for (int m = 0; m < 4; ++m) {
#pragma unroll
      for (int p = 0; p < 2; ++p) {
#pragma unroll
        for (int r = 0; r < 4; ++r) {
          const int row = m0 + wm + m * 16 + cg + r;
          const float av = acc[m][2 * p][r], gv = acc[m][2 * p + 1][r];
          const float ge = 0.5f * gv * (1.0f + erff(gv * 0.70710678118654752f)) * av;
          Cb[(size_t)row * N + jbase + p * 16] = (bf16)ge;
        }
      }
    }
  } else {
#pragma unroll
    for (int m = 0; m < 4; ++m) {
#pragma unroll
      for (int n = 0; n < 4; ++n) {
        const int col = n0 + wn + n * 16 + cc;
#pragma unroll
        for (int r = 0; r < 4; ++r) {
          const int row = m0 + wm + m * 16 + cg + r;
          const size_t idx = (size_t)row * N + col;
          if (MODE == 0) Cb[idx] = (bf16)acc[m][n][r];
          else           Xr[idx] += acc[m][n][r];
        }
      }
    }
  }
}

// ======================= V transpose: VT[b][dh][n] = QKV[b*NN+n][576+dh] ==========
__global__ void vt_kernel(const bf16* __restrict__ QKV, bf16* __restrict__ VT) {
  __shared__ bf16 t[32][33];
  const int n0 = blockIdx.x * 32, d0 = blockIdx.y * 32, b = blockIdx.z;
  const int tx = threadIdx.x, ty = threadIdx.y;
#pragma unroll
  for (int k = 0; k < 4; ++k) {
    int n = n0 + ty + k * 8;
    t[ty + k * 8][tx] = QKV[(size_t)(b * NN + n) * QKVN + 576 + d0 + tx];
  }
  __syncthreads();
#pragma unroll
  for (int k = 0; k < 4; ++k) {
    int dh = d0 + ty + k * 8;
    VT[(size_t)(b * 64 + dh) * NN + n0 + tx] = t[tx][ty + k * 8];
  }
}

// ======================= attention: 32x32 MFMA, in-register softmax ==============
// 4 waves/block = 4 heads (MQA: K/V shared -> L1 reuse), no barriers, no LDS.
// NSPLIT=4 KV splits -> 1024 blocks = 4 waves/SIMD co-resident. Partials in
// q-major layout Opart[split][bh][q][64] so combine reads are coalesced.
__launch_bounds__(256)
__global__ void attn_kernel(const bf16* __restrict__ QKV, const bf16* __restrict__ VT,
                            const float* __restrict__ btab,
                            float* __restrict__ Opart, float* __restrict__ mlbuf) {
  const int tid = threadIdx.x;
  const int lane = tid & 63, wv = tid >> 6;
  const int split = blockIdx.x & (NSPLIT - 1);
  const int qt = (NN / 32 - 1) - (blockIdx.x / NSPLIT);   // longest-first
  const int h = blockIdx.y * 4 + wv, b = blockIdx.z;
  const int q0 = qt * 32;
  const int qc = lane & 31;        // q col (also A-operand row index, also V^T d row)
  const int hid = lane >> 5;
  const int h8 = hid * 8;
  const int kv_full = q0 + 32;
  // distribute 32-row tiles among NSPLIT splits
  const int nt32 = kv_full >> 5;
  const int base = nt32 >> 2, rem = nt32 & 3;
  const int cnt = base + (split < rem ? 1 : 0);
  const int startT = split * base + (split < rem ? split : rem);
  const int lo = startT * 32;
  const int kend = lo + cnt * 32;
  const size_t obase = ((size_t)(split * NB * NH) + b * NH + h) * NN;  // q-row base
  const int Rbase = (b * NH + h) * NN + q0;
  float* prow = Opart + (obase + q0 + qc) * 64;
  if (cnt == 0) {   // empty split: zero partial block, weight 0 in combine
#pragma unroll
    for (int dd = 0; dd < 32; ++dd) prow[dd * 2 + hid] = 0.0f;
    if (hid == 0)
      ((float2*)mlbuf)[(size_t)split * AROWS + Rbase + qc] = make_float2(-1e30f, 0.0f);
    return;
  }
  const float* bt = btab + h * NN;
  bf16x8 qf[4];
#pragma unroll
  for (int ks = 0; ks < 4; ++ks)
    qf[ks] = *(const bf16x8*)&QKV[(size_t)(b * NN + q0 + qc) * QKVN + h * DH + ks * 16 + h8];

  f32x16 Oacc0 = {}, Oacc1 = {};
  float m_run = -1e30f, l_run = 0.0f;
  int kv0 = lo;

  while (kv0 < kend) {
    const bool interior = (kv0 + 32 <= q0);
    bf16x8 kf[4];
#pragma unroll
    for (int ks = 0; ks < 4; ++ks)
      kf[ks] = *(const bf16x8*)&QKV[(size_t)(b * NN + kv0 + qc) * QKVN + 512 + ks * 16 + h8];
    bf16x8 vf[2][2];
#pragma unroll
    for (int dblk = 0; dblk < 2; ++dblk)
#pragma unroll
      for (int ks2 = 0; ks2 < 2; ++ks2)
        vf[dblk][ks2] = *(const bf16x8*)&VT[(size_t)(b * 64 + dblk * 32 + qc) * NN + kv0 + ks2 * 16 + h8];
    __builtin_amdgcn_s_setprio(1);
    f32x16 S = {};
#pragma unroll
    for (int ks = 0; ks < 4; ++ks)
      S = __builtin_amdgcn_mfma_f32_32x32x16_bf16(kf[ks], qf[ks], S, 0, 0, 0);
    __builtin_amdgcn_s_setprio(0);
    float sv[16];
    float mx = -1e30f;
    if (interior) {
      f32x4 bv[4];
#pragma unroll
      for (int g = 0; g < 4; ++g)
        bv[g] = *(const f32x4u*)(bt + (q0 + qc - kv0 - 8 * g - 4 * hid - 3));
#pragma unroll
      for (int g = 0; g < 4; ++g)
#pragma unroll
        for (int e = 0; e < 4; ++e) {
          const float val = S[g * 4 + e] + bv[g][3 - e];
          sv[g * 4 + e] = val;
          mx = fmaxf(mx, val);
        }
    } else {
#pragma unroll
      for (int r = 0; r < 16; ++r) {
        const int kvr = (r & 3) + 8 * (r >> 2) + 4 * hid;
        const int d = (q0 + qc) - (kv0 + kvr);
        const int dc = d > 0 ? d : 0;
        float val = S[r] + bt[dc];
        if (d < 0) val = -1e30f;
        sv[r] = val;
        mx = fmaxf(mx, val);
      }
    }
    if (!__all(mx <= m_run + 8.0f)) {
      mx = fmaxf(mx, __shfl_xor(mx, 32));
      const float m_new = fmaxf(m_run, mx);
      const float sc = __expf(m_run - m_new);
      l_run *= sc;
#pragma unroll
      for (int r = 0; r < 16; ++r) { Oacc0[r] *= sc; Oacc1[r] *= sc; }
      m_run = m_new;
    }
    float csum = 0.0f;
#pragma unroll
    for (int r = 0; r < 16; ++r) { sv[r] = __expf(sv[r] - m_run); csum += sv[r]; }
    csum += __shfl_xor(csum, 32);
    l_run += csum;
    int w[8];
#pragma unroll
    for (int g = 0; g < 4; ++g) {
      w[2 * g]     = pack_bf16(sv[4 * g],     sv[4 * g + 1]);
      w[2 * g + 1] = pack_bf16(sv[4 * g + 2], sv[4 * g + 3]);
    }
    bf16x8 pfrag[2];
#pragma unroll
    for (int ks2 = 0; ks2 < 2; ++ks2) {
      const int a  = w[4 * ks2],     bb = w[4 * ks2 + 1];
      const int c  = w[4 * ks2 + 2], dd = w[4 * ks2 + 3];
      const int s0 = hid ? a : c,    s1 = hid ? bb : dd;
      const int r0 = __shfl_xor(s0, 32);
      const int r1 = __shfl_xor(s1, 32);
      i32x4 fw;
      fw[0] = hid ? r0 : a;
      fw[1] = hid ? r1 : bb;
      fw[2] = hid ? c  : r0;
      fw[3] = hid ? dd : r1;
      pfrag[ks2] = __builtin_bit_cast(bf16x8, fw);
    }
    __builtin_amdgcn_s_setprio(1);
#pragma unroll
    for (int ks2 = 0; ks2 < 2; ++ks2) {
      Oacc0 = __builtin_amdgcn_mfma_f32_32x32x16_bf16(vf[0][ks2], pfrag[ks2], Oacc0, 0, 0, 0);
      Oacc1 = __builtin_amdgcn_mfma_f32_32x32x16_bf16(vf[1][ks2], pfrag[ks2], Oacc1, 0, 0, 0);
    }
    __builtin_amdgcn_s_setprio(0);
    kv0 += 32;
  }
#pragma unroll
  for (int r = 0; r < 16; ++r) {
    const int dl = (r & 3) + 8 * (r >> 2) + 4 * hid;
    prow[dl]      = Oacc0[r];
    prow[32 + dl] = Oacc1[r];
  }
  if (hid == 0)
    ((float2*)mlbuf)[(size_t)split * AROWS + Rbase + qc] = make_float2(m_run, l_run);
}

// ======================= combine split-KV partials -> O (bf16) =================
// Opart layout: [split][bh][NN q][64 d] f32 (q-major), dq-fastest thread mapping.
__global__ void attn_combine(const float* __restrict__ Opart, const float* __restrict__ mlbuf,
                             bf16* __restrict__ O) {
  const int gtid = blockIdx.x * 256 + threadIdx.x;   // NB*NH*NN*16 threads
  const int dq = gtid & 15;
  const int q  = (gtid >> 4) & (NN - 1);
  const int bh = gtid >> 15;                          // b*NH + h
  const int R = bh * NN + q;
  float2 ml[NSPLIT];
  float m = -1e30f;
#pragma unroll
  for (int s = 0; s < NSPLIT; ++s) {
    ml[s] = ((const float2*)mlbuf)[(size_t)s * AROWS + R];
    m = fmaxf(m, ml[s].x);
  }
  float w[NSPLIT];
  float denom = 0.0f;
#pragma unroll
  for (int s = 0; s < NSPLIT; ++s) {
    w[s] = __expf(ml[s].x - m);
    denom += ml[s].y * w[s];
  }
  const float inv = 1.0f / denom;
  float o[4] = {};
#pragma unroll
  for (int s = 0; s < NSPLIT; ++s) {
    const f32x4 v = *(const f32x4*)(Opart + ((size_t)(s * NB * NH + bh) * NN + q) * 64 + dq * 4);
#pragma unroll
    for (int j = 0; j < 4; ++j) o[j] += v[j] * w[s];
  }
  bf16x4 res;
#pragma unroll
  for (int j = 0; j < 4; ++j) res[j] = (bf16)(o[j] * inv);
  const int h = bh & (NH - 1), b = bh >> 3;
  *(bf16x4*)&O[(size_t)(b * NN + q) * INNER + h * DH + dq * 4] = res;
}

// ======================= launch ==========================
extern "C" void kernel_launch(void* const* d_in, const int* in_sizes, int n_in,
                              void* d_out, int out_size, void* d_ws, size_t ws_size,
                              hipStream_t stream) {
  (void)in_sizes; (void)n_in; (void)out_size;
  const float* in_x  = (const float*)d_in[0];
  const float* rel   = (const float*)d_in[1];
  const float* ln1g  = (const float*)d_in[2];
  const float* ln1b  = (const float*)d_in[3];
  const float* wq    = (const float*)d_in[4];
  const float* wkv   = (const float*)d_in[5];
  const float* wo    = (const float*)d_in[6];
  const float* ln2g  = (const float*)d_in[7];
  const float* ln2b  = (const float*)d_in[8];
  const float* w1    = (const float*)d_in[9];
  const float* w2    = (const float*)d_in[10];
  const float* lnfg  = (const float*)d_in[11];
  const float* lnfb  = (const float*)d_in[12];
  float* out = (float*)d_out;

  constexpr size_t E_QKV = (size_t)QKVN * DIM;   // fused wq|wkv, [640][1024]
  constexpr size_t E_WO  = (size_t)DIM * INNER;
  constexpr size_t E_W1F = (size_t)FF2N * DIM;   // interleaved a/g [5632][1024]
  constexpr size_t E_W2  = (size_t)DIM * FFP;
  bf16* wqkvT = (bf16*)d_ws;
  bf16* woT  = wqkvT + NLAY * E_QKV;
  bf16* w1fT = woT  + NLAY * E_WO;
  bf16* w2T  = w1fT + NLAY * E_W1F;
  bf16* xnb  = w2T  + NLAY * E_W2;
  bf16* qkvb = xnb  + (size_t)MROW * DIM;
  bf16* vTb  = qkvb + (size_t)MROW * QKVN;
  bf16* ob   = vTb  + (size_t)NB * 64 * NN;
  bf16* hb   = ob   + (size_t)MROW * INNER;      // FF phase: compact [4096][FFP]
  float* xbuf = (float*)(hb + (size_t)MROW * FF2N);
  float* btab = xbuf + (size_t)MROW * DIM;
  const size_t needed = (size_t)((char*)(btab + NH * NN) - (char*)d_ws);
  if (ws_size < needed) return;  // visible clean failure instead of corruption
  // attn partials overlaid on hb (FF phase and attn phase are disjoint in time):
  float* Opart = (float*)hb;
  float* mlbuf = (float*)(hb + (size_t)18 * 1024 * 1024);
  hipMemcpyAsync(xbuf, in_x, (size_t)MROW * DIM * sizeof(float),
                 hipMemcpyDeviceToDevice, stream);
  btab_kernel<<<8, 256, 0, stream>>>(rel, btab);

  const dim3 tb(32, 8);
  conv_tr<<<dim3(16, 32, 6), tb, 0, stream>>>(wq,  (size_t)DIM*INNER, INNER, 0, DIM, INNER,
                                              wqkvT, E_QKV, DIM, 0.125f, -1);  // fold DH^-0.5
  conv_tr<<<dim3(4, 32, 6),  tb, 0, stream>>>(wkv, (size_t)DIM*128, 128, 0, DIM, 128,
                                              wqkvT + (size_t)INNER*DIM, E_QKV, DIM, 1.0f, -1);
  conv_tr<<<dim3(32, 16, 6), tb, 0, stream>>>(wo,  (size_t)INNER*DIM, DIM, 0, INNER, DIM,
                                              woT,  E_WO, INNER, 1.0f, -1);
  conv_tr<<<dim3(88, 32, 6), tb, 0, stream>>>(w1,  (size_t)DIM*2*FF, 2*FF, 0, DIM, FF,
                                              w1fT, E_W1F, DIM, 1.0f, 0);    // a rows -> +0
  conv_tr<<<dim3(88, 32, 6), tb, 0, stream>>>(w1,  (size_t)DIM*2*FF, 2*FF, FF, DIM, FF,
                                              w1fT, E_W1F, DIM, 1.0f, 16);   // g rows -> +16
  conv_tr<<<dim3(32, 88, 6), tb, 0, stream>>>(w2,  (size_t)FF*DIM, DIM, 0, FF, DIM,
                                              w2T,  E_W2, FFP, 1.0f, -1);

  for (int l = 0; l < NLAY; ++l) {
    ln_kernel<bf16><<<MROW, 256, 0, stream>>>(xbuf, ln1g + l*DIM, ln1b + l*DIM, xnb);
    gemm_bt<0><<<dim3(QKVN/128, MROW/128), 512, 0, stream>>>(xnb, wqkvT + l*E_QKV, DIM, DIM, QKVN, qkvb, nullptr);
    vt_kernel<<<dim3(NN/32, 2, NB), tb, 0, stream>>>(qkvb, vTb);
    attn_kernel<<<dim3((NN/32)*NSPLIT, NH/4, NB), 256, 0, stream>>>(qkvb, vTb, btab, Opart, mlbuf);
    attn_combine<<<AROWS*16/256, 256, 0, stream>>>(Opart, mlbuf, ob);
    gemm_bt<1><<<dim3(DIM/128, MROW/128), 512, 0, stream>>>(ob, woT + l*E_WO, INNER, INNER, DIM, nullptr, xbuf);
    ln_kernel<bf16><<<MROW, 256, 0, stream>>>(xbuf, ln2g + l*DIM, ln2b + l*DIM, xnb);
    gemm97<2><<<dim3(FF2N/128, MROW/128), 256, 0, stream>>>(xnb, w1fT + l*E_W1F, DIM, DIM, FFP, hb, nullptr);
    gemm_bt<1><<<dim3(DIM/128, MROW/128), 512, 0, stream>>>(hb, w2T + l*E_W2, FFP, FFP, DIM, nullptr, xbuf);
  }
  ln_kernel<float><<<MROW, 256, 0, stream>>>(xbuf, lnfg, lnfb, out);
}